// Round 12
// baseline (545.392 us; speedup 1.0000x reference)
//
#include <hip/hip_runtime.h>
#include <hip/hip_fp16.h>
#include <math.h>

#define N 6000
#define FIN 300
#define HID 128
#define NH 8
#define ALPHA 0.2f
#define NBR_CAP 512
#define KSPLIT 8
#define TMM 128
#define KC 64
#define NCH ((N + KC - 1) / KC)   // 94

typedef unsigned short u16;
typedef unsigned int u32;
typedef short bf16x8 __attribute__((ext_vector_type(8)));
typedef float f32x4 __attribute__((ext_vector_type(4)));

static __device__ __forceinline__ u16 f2bf(float f) {
    u32 u = __float_as_uint(f);
    u32 r = (u + 0x7fff + ((u >> 16) & 1)) >> 16;   // round-to-nearest-even
    return (u16)r;
}
static __device__ __forceinline__ u16 f2h(float f) {
    return __half_as_ushort(__float2half(f));
}

// K0: build neighbor lists, GLOBALLY ASCENDING in m (lane-major compaction).
__global__ void build_nbr(const float* __restrict__ adj,
                          u16* __restrict__ nbr,
                          int* __restrict__ ncnt) {
    int n = blockIdx.x;
    int t = threadIdx.x;
    int lane = t & 63, w = t >> 6;
    __shared__ u16 lbuf[4][256];
    __shared__ int wc[4];
    const int seg = N / 4;                 // 1500
    int start = w * seg, end = start + seg;
    const float* row = adj + (size_t)n * N;
    int cnt = 0;
    for (int base = start; base < end; base += 256) {
        int m0 = base + 4 * lane;
        float4 v = make_float4(0.f, 0.f, 0.f, 0.f);
        if (m0 < end) v = *(const float4*)(row + m0);
        bool p0 = v.x > 0.5f, p1 = v.y > 0.5f, p2 = v.z > 0.5f, p3 = v.w > 0.5f;
        unsigned long long mk0 = __ballot(p0);
        unsigned long long mk1 = __ballot(p1);
        unsigned long long mk2 = __ballot(p2);
        unsigned long long mk3 = __ballot(p3);
        unsigned long long below = (1ull << lane) - 1ull;
        int off = cnt + __popcll(mk0 & below) + __popcll(mk1 & below)
                      + __popcll(mk2 & below) + __popcll(mk3 & below);
        if (p0) { if (off < 256) lbuf[w][off] = (u16)(m0 + 0); off++; }
        if (p1) { if (off < 256) lbuf[w][off] = (u16)(m0 + 1); off++; }
        if (p2) { if (off < 256) lbuf[w][off] = (u16)(m0 + 2); off++; }
        if (p3) { if (off < 256) lbuf[w][off] = (u16)(m0 + 3); off++; }
        cnt += __popcll(mk0) + __popcll(mk1) + __popcll(mk2) + __popcll(mk3);
    }
    if (cnt > 256) cnt = 256;
    if (lane == 0) wc[w] = cnt;
    __syncthreads();
    int offset = 0;
    for (int i = 0; i < w; i++) offset += wc[i];
    for (int i = lane; i < cnt; i += 64) {
        int idx = offset + i;
        if (idx < NBR_CAP) nbr[(size_t)n * NBR_CAP + idx] = lbuf[w][i];
    }
    if (t == 0) {
        int total = wc[0] + wc[1] + wc[2] + wc[3];
        ncnt[n] = total < NBR_CAP ? total : NBR_CAP;
    }
}

// K1: x @ W_heads -> WhbT[h][c][m] (bf16, direct store from acc), fused f1/f2.
__global__ void gemm_wh(const float* __restrict__ x,
                        const float* __restrict__ W,
                        const float* __restrict__ a_heads,
                        u16* __restrict__ WhbT,
                        float* __restrict__ f1, float* __restrict__ f2) {
    int h = blockIdx.y;
    int n0 = blockIdx.x * 64;
    __shared__ float xs[64][21];
    __shared__ float bs[20][128];
    int t = threadIdx.x;
    int tx = t & 31, ty = t >> 5;
    float acc[8][4] = {};
    for (int k0 = 0; k0 < FIN; k0 += 20) {
        for (int i = t; i < 64 * 20; i += 256) {
            int r = i / 20, c = i - r * 20;
            int n = n0 + r;
            xs[r][c] = (n < N) ? x[(size_t)n * FIN + k0 + c] : 0.f;
        }
        for (int i = t; i < 20 * 128; i += 256) {
            int r = i >> 7, c = i & 127;
            bs[r][c] = W[((size_t)h * FIN + (k0 + r)) * HID + c];
        }
        __syncthreads();
#pragma unroll
        for (int kk = 0; kk < 20; kk++) {
            float b[4];
#pragma unroll
            for (int j = 0; j < 4; j++) b[j] = bs[kk][tx * 4 + j];
#pragma unroll
            for (int i = 0; i < 8; i++) {
                float a = xs[ty * 8 + i][kk];
#pragma unroll
                for (int j = 0; j < 4; j++) acc[i][j] += a * b[j];
            }
        }
        __syncthreads();
    }
    float a1c[4], a2c[4];
#pragma unroll
    for (int j = 0; j < 4; j++) {
        a1c[j] = a_heads[(size_t)h * 2 * HID + tx * 4 + j];
        a2c[j] = a_heads[(size_t)h * 2 * HID + HID + tx * 4 + j];
    }
    for (int i = 0; i < 8; i++) {
        int n = n0 + ty * 8 + i;
        float s1 = 0.f, s2 = 0.f;
#pragma unroll
        for (int j = 0; j < 4; j++) { s1 += acc[i][j] * a1c[j]; s2 += acc[i][j] * a2c[j]; }
        for (int d = 1; d <= 16; d <<= 1) { s1 += __shfl_xor(s1, d); s2 += __shfl_xor(s2, d); }
        if (n < N && tx == 0) { f1[h * N + n] = s1; f2[h * N + n] = s2; }
    }
    bool fast = (n0 + 64 <= N);
#pragma unroll
    for (int j = 0; j < 4; j++) {
        int c = tx * 4 + j;
        u16* dst = WhbT + ((size_t)h * HID + c) * N + n0 + ty * 8;
        if (fast) {
            u32 w0 = (u32)f2bf(acc[0][j]) | ((u32)f2bf(acc[1][j]) << 16);
            u32 w1 = (u32)f2bf(acc[2][j]) | ((u32)f2bf(acc[3][j]) << 16);
            u32 w2 = (u32)f2bf(acc[4][j]) | ((u32)f2bf(acc[5][j]) << 16);
            u32 w3 = (u32)f2bf(acc[6][j]) | ((u32)f2bf(acc[7][j]) << 16);
            *(uint4*)dst = make_uint4(w0, w1, w2, w3);
        } else {
            for (int i = 0; i < 8; i++)
                if (n0 + ty * 8 + i < N) dst[i] = f2bf(acc[i][j]);
        }
    }
}

// K2b: calc_w — precompute bf16 softmax weights for all heads + fp32 row sums.
__global__ void calc_w(const float* __restrict__ f1, const float* __restrict__ f2,
                       const u16* __restrict__ nbr, const int* __restrict__ ncnt,
                       u16* __restrict__ wl, float* __restrict__ swsum) {
    int n = blockIdx.x, t = threadIdx.x;
    int lane = t & 63, w = t >> 6;
    int cnt = ncnt[n];
    const u16* lst = nbr + (size_t)n * NBR_CAP;
    float f1c[NH];
#pragma unroll
    for (int h = 0; h < NH; h++) f1c[h] = f1[h * N + n];
    float ps[NH] = {};
    for (int i = t; i < cnt; i += 256) {
        int m = lst[i];
#pragma unroll
        for (int h = 0; h < NH; h++) {
            float z = f1c[h] + f2[h * N + m];
            z = (z >= 0.f) ? z : ALPHA * z;
            u16 bw = f2bf(__expf(z));
            wl[((size_t)h * N + n) * NBR_CAP + i] = bw;
            ps[h] += __uint_as_float((u32)bw << 16);
        }
    }
    __shared__ float red[4][NH];
#pragma unroll
    for (int h = 0; h < NH; h++) {
        float s = ps[h];
        for (int d = 1; d <= 32; d <<= 1) s += __shfl_xor(s, d);
        if (lane == 0) red[w][h] = s;
    }
    __syncthreads();
    if (t < NH) swsum[t * N + n] = red[0][t] + red[1][t] + red[2][t] + red[3][t];
}

// K3: layer-1 PV via MFMA, TM=128, double-buffered Pl/Bt, 1 barrier/chunk.
// 512 thr = 8 waves: waves 0-1 scatter P[next], waves 2-5 stage B[next],
// all 8 waves MFMA on current buffer. XOR swizzle ((row&7)<<3) both sides.
__global__ __launch_bounds__(512, 4)
void gat1_mfma(const u16* __restrict__ WhbT,
               const u16* __restrict__ wl, const float* __restrict__ swsum,
               const u16* __restrict__ nbr, const int* __restrict__ ncnt,
               float* __restrict__ hcat) {
    int h = blockIdx.x, tile = blockIdx.y;
    int n0 = tile * TMM;
    int t = threadIdx.x;
    int lane = t & 63, wid = t >> 6;
    int l4 = lane >> 4, lr = lane & 15;

    __shared__ u16 Pl[2][TMM][KC];   // 32 KB
    __shared__ u16 Bt[2][HID][KC];   // 32 KB

    // scatter role (threads 0..127): one destination row each, reg-FIFO walk
    int cnt = 0;
    const u16* lst = nullptr;
    const u16* wrow = nullptr;
    int xr = (t & 7) << 3;
    int p = 0;
    int fm0 = 0x7fffffff, fm1 = 0x7fffffff, fm2 = 0x7fffffff, fm3 = 0x7fffffff;
    if (t < TMM) {
        int nrow = n0 + t;
        if (nrow < N) {
            cnt = ncnt[nrow];
            lst = nbr + (size_t)nrow * NBR_CAP;
            wrow = wl + ((size_t)h * N + nrow) * NBR_CAP;
            fm0 = (0 < cnt) ? (int)lst[0] : 0x7fffffff;
            fm1 = (1 < cnt) ? (int)lst[1] : 0x7fffffff;
            fm2 = (2 < cnt) ? (int)lst[2] : 0x7fffffff;
            fm3 = (3 < cnt) ? (int)lst[3] : 0x7fffffff;
        }
    }
    const u16* wsrc = WhbT + (size_t)h * HID * N;
    int st = t - TMM;                // staging threads: st in [0,256)
    int sc = st & 127;               // B row (col of Wh)
    int sg = (st >> 7) & 1;          // half: 0 -> m..m+32, 1 -> m+32..m+64
    int cx = (sc & 7) << 3;
    bool is_stage = (t >= TMM && st < 256);

    f32x4 acc[8];
#pragma unroll
    for (int ct = 0; ct < 8; ct++) acc[ct] = (f32x4){0.f, 0.f, 0.f, 0.f};

    // ---- prologue: chunk 0 into buffer 0
    if (t < TMM) {
        uint4 z4 = make_uint4(0u, 0u, 0u, 0u);
#pragma unroll
        for (int j = 0; j < 8; j++) *(uint4*)&Pl[0][t][(8 * j) ^ xr] = z4;
        while (fm0 < KC) {
            Pl[0][t][fm0 ^ xr] = wrow[p];
            p++;
            fm0 = fm1; fm1 = fm2; fm2 = fm3;
            int i3 = p + 3;
            fm3 = (i3 < cnt) ? (int)lst[i3] : 0x7fffffff;
        }
    } else if (is_stage) {
        int mb = sg * 32;
        const u16* src = wsrc + (size_t)sc * N + mb;
        uint4 v0 = ((const uint4*)src)[0];
        uint4 v1 = ((const uint4*)src)[1];
        uint4 v2 = ((const uint4*)src)[2];
        uint4 v3 = ((const uint4*)src)[3];
        *(uint4*)&Bt[0][sc][(sg * 32 + 0)  ^ cx] = v0;
        *(uint4*)&Bt[0][sc][(sg * 32 + 8)  ^ cx] = v1;
        *(uint4*)&Bt[0][sc][(sg * 32 + 16) ^ cx] = v2;
        *(uint4*)&Bt[0][sc][(sg * 32 + 24) ^ cx] = v3;
    }
    __syncthreads();

    int axr = (lr & 7) << 3;
    for (int ch = 0; ch < NCH; ch++) {
        int cur = ch & 1, nxt = cur ^ 1;
        bool have_next = (ch + 1 < NCH);
        // issue B loads for next chunk early (waves 2-5)
        uint4 v0, v1, v2, v3;
        if (have_next && is_stage) {
            int mb = (ch + 1) * KC + sg * 32;
            const u16* src = wsrc + (size_t)sc * N + mb;
            if (mb + 32 <= N) {
                v0 = ((const uint4*)src)[0];
                v1 = ((const uint4*)src)[1];
                v2 = ((const uint4*)src)[2];
                v3 = ((const uint4*)src)[3];
            } else {
                u16 tmp[32];
#pragma unroll
                for (int j = 0; j < 32; j++) tmp[j] = (mb + j < N) ? src[j] : (u16)0;
                v0 = ((const uint4*)tmp)[0]; v1 = ((const uint4*)tmp)[1];
                v2 = ((const uint4*)tmp)[2]; v3 = ((const uint4*)tmp)[3];
            }
        }
        // scatter P for next chunk (waves 0-1)
        if (have_next && t < TMM) {
            int m0n = (ch + 1) * KC, mendn = m0n + KC;
            uint4 z4 = make_uint4(0u, 0u, 0u, 0u);
#pragma unroll
            for (int j = 0; j < 8; j++) *(uint4*)&Pl[nxt][t][(8 * j) ^ xr] = z4;
            while (fm0 < mendn) {
                Pl[nxt][t][(fm0 - m0n) ^ xr] = wrow[p];
                p++;
                fm0 = fm1; fm1 = fm2; fm2 = fm3;
                int i3 = p + 3;
                fm3 = (i3 < cnt) ? (int)lst[i3] : 0x7fffffff;
            }
        }
        // MFMA on current buffer (all 8 waves; wave owns 16 rows)
        int arow = 16 * wid + lr;
#pragma unroll
        for (int ks = 0; ks < 2; ks++) {
            int kb = ks * 32 + 8 * l4;
            bf16x8 a = *(const bf16x8*)&Pl[cur][arow][kb ^ axr];
#pragma unroll
            for (int ct = 0; ct < 8; ct++) {
                bf16x8 b = *(const bf16x8*)&Bt[cur][16 * ct + lr][kb ^ axr];
                acc[ct] = __builtin_amdgcn_mfma_f32_16x16x32_bf16(a, b, acc[ct], 0, 0, 0);
            }
        }
        // write staged B regs to next buffer
        if (have_next && is_stage) {
            *(uint4*)&Bt[nxt][sc][(sg * 32 + 0)  ^ cx] = v0;
            *(uint4*)&Bt[nxt][sc][(sg * 32 + 8)  ^ cx] = v1;
            *(uint4*)&Bt[nxt][sc][(sg * 32 + 16) ^ cx] = v2;
            *(uint4*)&Bt[nxt][sc][(sg * 32 + 24) ^ cx] = v3;
        }
        __syncthreads();
    }
    // epilogue: C/D col = lane&15, row = 4*(lane>>4)+reg (R10/R11-verified)
#pragma unroll
    for (int reg = 0; reg < 4; reg++) {
        int rl = 16 * wid + 4 * l4 + reg;
        int n = n0 + rl;
        if (n < N) {
            float inv = 1.f / swsum[h * N + n];
            float* orow = hcat + (size_t)n * (NH * HID) + h * HID;
#pragma unroll
            for (int ct = 0; ct < 8; ct++) {
                float v = acc[ct][reg] * inv;
                v = (v > 0.f) ? v : expm1f(v);
                orow[16 * ct + lr] = v;
            }
        }
    }
}

// K4: partial = hcat(6000x1024) @ W_out(1024x128), split-K over 8 slices.
__global__ void gemm_out(const float* __restrict__ hcat,
                         const float* __restrict__ W_out,
                         float* __restrict__ partial) {
    int n0 = blockIdx.x * 64;
    int ks = blockIdx.y;
    __shared__ float xs[64][17];
    __shared__ float bs[16][128];
    int t = threadIdx.x;
    int tx = t & 31, ty = t >> 5;
    float acc[8][4] = {};
    int kbeg = ks * 128, kend = kbeg + 128;
    for (int k0 = kbeg; k0 < kend; k0 += 16) {
        for (int i = t; i < 64 * 16; i += 256) {
            int r = i >> 4, c = i & 15;
            int n = n0 + r;
            xs[r][c] = (n < N) ? hcat[(size_t)n * 1024 + k0 + c] : 0.f;
        }
        for (int i = t; i < 16 * 128; i += 256) {
            int r = i >> 7, c = i & 127;
            bs[r][c] = W_out[(size_t)(k0 + r) * HID + c];
        }
        __syncthreads();
#pragma unroll
        for (int kk = 0; kk < 16; kk++) {
            float b[4];
#pragma unroll
            for (int j = 0; j < 4; j++) b[j] = bs[kk][tx * 4 + j];
#pragma unroll
            for (int i = 0; i < 8; i++) {
                float a = xs[ty * 8 + i][kk];
#pragma unroll
                for (int j = 0; j < 4; j++) acc[i][j] += a * b[j];
            }
        }
        __syncthreads();
    }
    float* pout = partial + (size_t)ks * N * HID;
    for (int i = 0; i < 8; i++) {
        int n = n0 + ty * 8 + i;
        if (n < N) {
#pragma unroll
            for (int j = 0; j < 4; j++)
                pout[(size_t)n * HID + tx * 4 + j] = acc[i][j];
        }
    }
}

// K4b: sum the 8 K-split partials -> fp16 Wh2h shadow; fused g1/g2.
__global__ void reduce_wh2(const float* __restrict__ partial,
                           const float* __restrict__ a_out,
                           u16* __restrict__ Wh2h,
                           float* __restrict__ g1, float* __restrict__ g2) {
    int idx = blockIdx.x * 256 + threadIdx.x;      // float4 index
    float4 v = *(const float4*)(partial + 4 * (size_t)idx);
#pragma unroll
    for (int s = 1; s < KSPLIT; s++) {
        const float4 q = *(const float4*)(partial + (size_t)s * N * HID + 4 * (size_t)idx);
        v.x += q.x; v.y += q.y; v.z += q.z; v.w += q.w;
    }
    ushort4 h4;
    h4.x = f2h(v.x); h4.y = f2h(v.y); h4.z = f2h(v.z); h4.w = f2h(v.w);
    *(ushort4*)(Wh2h + 4 * (size_t)idx) = h4;

    int row = idx >> 5, cg = idx & 31;
    float p1 = v.x * a_out[4 * cg] + v.y * a_out[4 * cg + 1]
             + v.z * a_out[4 * cg + 2] + v.w * a_out[4 * cg + 3];
    float p2 = v.x * a_out[HID + 4 * cg] + v.y * a_out[HID + 4 * cg + 1]
             + v.z * a_out[HID + 4 * cg + 2] + v.w * a_out[HID + 4 * cg + 3];
    for (int d = 1; d <= 16; d <<= 1) { p1 += __shfl_xor(p1, d); p2 += __shfl_xor(p2, d); }
    if ((threadIdx.x & 31) == 0) { g1[row] = p1; g2[row] = p2; }
}

// K6: layer-2 fused masked-softmax + PV, fp16 gather.
__global__ void gat2(const u16* __restrict__ Wh2h,
                     const float* __restrict__ g1, const float* __restrict__ g2,
                     const u16* __restrict__ nbr,
                     const int* __restrict__ ncnt,
                     float* __restrict__ out) {
    int n = blockIdx.x, t = threadIdx.x;
    int s = t >> 4, op = t & 15;
    int cnt = ncnt[n];
    const u16* lst = nbr + (size_t)n * NBR_CAP;
    __shared__ float2 wm[NBR_CAP];
    __shared__ float accl[16][16][9];
    __shared__ float swl[16];

    float g1c = g1[n];
    for (int i = t; i < cnt; i += 256) {
        int m = lst[i];
        float z = g1c + g2[m];
        z = (z >= 0.f) ? z : ALPHA * z;
        wm[i] = make_float2(__expf(z), __uint_as_float((u32)m << 8));
    }
    __syncthreads();

    const char* base = (const char*)Wh2h + (op << 4);
    float acc[8] = {};
    float sw = 0.f;
    int j = s;
    for (; j + 16 < cnt; j += 32) {
        float2 p0 = wm[j];
        float2 p1 = wm[j + 16];
        const uint4 va = *(const uint4*)(base + __float_as_uint(p0.y));
        const uint4 vb = *(const uint4*)(base + __float_as_uint(p1.y));
        float w0 = p0.x, w1 = p1.x;
        acc[0] += w0 * __half2float(__ushort_as_half((u16)(va.x & 0xffff)));
        acc[1] += w0 * __half2float(__ushort_as_half((u16)(va.x >> 16)));
        acc[2] += w0 * __half2float(__ushort_as_half((u16)(va.y & 0xffff)));
        acc[3] += w0 * __half2float(__ushort_as_half((u16)(va.y >> 16)));
        acc[4] += w0 * __half2float(__ushort_as_half((u16)(va.z & 0xffff)));
        acc[5] += w0 * __half2float(__ushort_as_half((u16)(va.z >> 16)));
        acc[6] += w0 * __half2float(__ushort_as_half((u16)(va.w & 0xffff)));
        acc[7] += w0 * __half2float(__ushort_as_half((u16)(va.w >> 16)));
        acc[0] += w1 * __half2float(__ushort_as_half((u16)(vb.x & 0xffff)));
        acc[1] += w1 * __half2float(__ushort_as_half((u16)(vb.x >> 16)));
        acc[2] += w1 * __half2float(__ushort_as_half((u16)(vb.y & 0xffff)));
        acc[3] += w1 * __half2float(__ushort_as_half((u16)(vb.y >> 16)));
        acc[4] += w1 * __half2float(__ushort_as_half((u16)(vb.z & 0xffff)));
        acc[5] += w1 * __half2float(__ushort_as_half((u16)(vb.z >> 16)));
        acc[6] += w1 * __half2float(__ushort_as_half((u16)(vb.w & 0xffff)));
        acc[7] += w1 * __half2float(__ushort_as_half((u16)(vb.w >> 16)));
        sw += w0 + w1;
    }
    if (j < cnt) {
        float2 p0 = wm[j];
        const uint4 va = *(const uint4*)(base + __float_as_uint(p0.y));
        float w0 = p0.x;
        acc[0] += w0 * __half2float(__ushort_as_half((u16)(va.x & 0xffff)));
        acc[1] += w0 * __half2float(__ushort_as_half((u16)(va.x >> 16)));
        acc[2] += w0 * __half2float(__ushort_as_half((u16)(va.y & 0xffff)));
        acc[3] += w0 * __half2float(__ushort_as_half((u16)(va.y >> 16)));
        acc[4] += w0 * __half2float(__ushort_as_half((u16)(va.z & 0xffff)));
        acc[5] += w0 * __half2float(__ushort_as_half((u16)(va.z >> 16)));
        acc[6] += w0 * __half2float(__ushort_as_half((u16)(va.w & 0xffff)));
        acc[7] += w0 * __half2float(__ushort_as_half((u16)(va.w >> 16)));
        sw += w0;
    }
#pragma unroll
    for (int c = 0; c < 8; c++) accl[s][op][c] = acc[c];
    if (op == 0) swl[s] = sw;
    __syncthreads();

    if (t < 128) {
        int c = t;
        float r = 0.f;
#pragma unroll
        for (int k = 0; k < 16; k++) r += accl[k][c >> 3][c & 7];
        float swt = 0.f;
#pragma unroll
        for (int k = 0; k < 16; k++) swt += swl[k];
        out[(size_t)n * HID + c] = r / swt;
    }
}

extern "C" void kernel_launch(void* const* d_in, const int* in_sizes, int n_in,
                              void* d_out, int out_size, void* d_ws, size_t ws_size,
                              hipStream_t stream) {
    const float* x       = (const float*)d_in[0];
    const float* adj     = (const float*)d_in[1];
    const float* W_heads = (const float*)d_in[2];
    const float* a_heads = (const float*)d_in[3];
    const float* W_out   = (const float*)d_in[4];
    const float* a_out   = (const float*)d_in[5];
    float* out = (float*)d_out;

    char* wsb = (char*)d_ws;
    size_t off = 0;
    auto alloc = [&](size_t bytes) {
        void* p = wsb + off;
        off += (bytes + 255) & ~(size_t)255;
        return p;
    };
    float* partial = (float*)alloc(sizeof(float) * (size_t)KSPLIT * N * HID); // 24.6 MB
    u16*   WhbT = (u16*)  alloc(sizeof(u16)   * (size_t)NH * HID * N);        // 12.3 MB
    float* hcat = (float*)alloc(sizeof(float) * (size_t)N * NH * HID);        // 24.6 MB
    u16*   Wh2h = (u16*)  alloc(sizeof(u16)   * (size_t)N * HID);
    u16*   wlb  = (u16*)  alloc(sizeof(u16)   * (size_t)NH * N * NBR_CAP);    // 49.2 MB
    float* swsum= (float*)alloc(sizeof(float) * (size_t)NH * N);
    float* f1   = (float*)alloc(sizeof(float) * (size_t)NH * N);
    float* f2   = (float*)alloc(sizeof(float) * (size_t)NH * N);
    float* g1   = (float*)alloc(sizeof(float) * (size_t)N);
    float* g2   = (float*)alloc(sizeof(float) * (size_t)N);
    u16* nbr    = (u16*)  alloc(sizeof(u16)   * (size_t)N * NBR_CAP);
    int* ncnt   = (int*)  alloc(sizeof(int)   * (size_t)N);

    hipLaunchKernelGGL(build_nbr, dim3(N), dim3(256), 0, stream, adj, nbr, ncnt);
    hipLaunchKernelGGL(gemm_wh, dim3((N + 63) / 64, NH), dim3(256), 0, stream,
                       x, W_heads, a_heads, WhbT, f1, f2);
    hipLaunchKernelGGL(calc_w, dim3(N), dim3(256), 0, stream,
                       f1, f2, nbr, ncnt, wlb, swsum);
    hipLaunchKernelGGL(gat1_mfma, dim3(NH, (N + TMM - 1) / TMM), dim3(512), 0, stream,
                       WhbT, wlb, swsum, nbr, ncnt, hcat);
    hipLaunchKernelGGL(gemm_out, dim3((N + 63) / 64, KSPLIT), dim3(256), 0, stream,
                       hcat, W_out, partial);
    hipLaunchKernelGGL(reduce_wh2, dim3(N * HID / 4 / 256), dim3(256), 0, stream,
                       partial, a_out, Wh2h, g1, g2);
    hipLaunchKernelGGL(gat2, dim3(N), dim3(256), 0, stream, Wh2h, g1, g2, nbr, ncnt, out);
}

// Round 13
// 344.598 us; speedup vs baseline: 1.5827x; 1.5827x over previous
//
#include <hip/hip_runtime.h>
#include <hip/hip_fp16.h>
#include <math.h>

#define N 6000
#define FIN 300
#define HID 128
#define NH 8
#define ALPHA 0.2f
#define NBR_CAP 512
#define KSPLIT 8

typedef unsigned short u16;
typedef unsigned int u32;

static __device__ __forceinline__ u16 f2bf(float f) {
    u32 u = __float_as_uint(f);
    u32 r = (u + 0x7fff + ((u >> 16) & 1)) >> 16;   // round-to-nearest-even
    return (u16)r;
}
static __device__ __forceinline__ u16 f2h(float f) {
    return __half_as_ushort(__float2half(f));
}

// K0: build neighbor lists; per-wave private segment, 1 barrier, float4 loads
__global__ void build_nbr(const float* __restrict__ adj,
                          u16* __restrict__ nbr,
                          int* __restrict__ ncnt) {
    int n = blockIdx.x;
    int t = threadIdx.x;
    int lane = t & 63, w = t >> 6;
    __shared__ u16 lbuf[4][256];
    __shared__ int wc[4];
    const int seg = N / 4;                 // 1500
    int start = w * seg, end = start + seg;
    const float* row = adj + (size_t)n * N;
    int cnt = 0;
    for (int base = start; base < end; base += 256) {
        int m0 = base + 4 * lane;
        float4 v = make_float4(0.f, 0.f, 0.f, 0.f);
        if (m0 < end) v = *(const float4*)(row + m0);
#pragma unroll
        for (int c = 0; c < 4; c++) {
            float vc = (c == 0) ? v.x : (c == 1) ? v.y : (c == 2) ? v.z : v.w;
            bool p = vc > 0.5f;
            unsigned long long mask = __ballot(p);
            if (p) {
                int pos = cnt + __popcll(mask & ((1ull << lane) - 1ull));
                if (pos < 256) lbuf[w][pos] = (u16)(m0 + c);
            }
            cnt += __popcll(mask);
        }
    }
    if (cnt > 256) cnt = 256;
    if (lane == 0) wc[w] = cnt;
    __syncthreads();
    int offset = 0;
    for (int i = 0; i < w; i++) offset += wc[i];
    for (int i = lane; i < cnt; i += 64) {
        int idx = offset + i;
        if (idx < NBR_CAP) nbr[(size_t)n * NBR_CAP + idx] = lbuf[w][i];
    }
    if (t == 0) {
        int total = wc[0] + wc[1] + wc[2] + wc[3];
        ncnt[n] = total < NBR_CAP ? total : NBR_CAP;
    }
}

// K1: Whb(bf16) = x @ W_heads, fused f1/f2 epilogue (fp32 accurate).
__global__ void gemm_wh(const float* __restrict__ x,
                        const float* __restrict__ W,
                        const float* __restrict__ a_heads,
                        u16* __restrict__ Whb,
                        float* __restrict__ f1, float* __restrict__ f2) {
    int h = blockIdx.y;
    int n0 = blockIdx.x * 64;
    __shared__ float xs[64][21];
    __shared__ float bs[20][128];
    int t = threadIdx.x;
    int tx = t & 31, ty = t >> 5;
    float acc[8][4] = {};
    for (int k0 = 0; k0 < FIN; k0 += 20) {
        for (int i = t; i < 64 * 20; i += 256) {
            int r = i / 20, c = i - r * 20;
            int n = n0 + r;
            xs[r][c] = (n < N) ? x[(size_t)n * FIN + k0 + c] : 0.f;
        }
        for (int i = t; i < 20 * 128; i += 256) {
            int r = i >> 7, c = i & 127;
            bs[r][c] = W[((size_t)h * FIN + (k0 + r)) * HID + c];
        }
        __syncthreads();
#pragma unroll
        for (int kk = 0; kk < 20; kk++) {
            float b[4];
#pragma unroll
            for (int j = 0; j < 4; j++) b[j] = bs[kk][tx * 4 + j];
#pragma unroll
            for (int i = 0; i < 8; i++) {
                float a = xs[ty * 8 + i][kk];
#pragma unroll
                for (int j = 0; j < 4; j++) acc[i][j] += a * b[j];
            }
        }
        __syncthreads();
    }
    float a1c[4], a2c[4];
#pragma unroll
    for (int j = 0; j < 4; j++) {
        a1c[j] = a_heads[(size_t)h * 2 * HID + tx * 4 + j];
        a2c[j] = a_heads[(size_t)h * 2 * HID + HID + tx * 4 + j];
    }
    for (int i = 0; i < 8; i++) {
        int n = n0 + ty * 8 + i;
        float s1 = 0.f, s2 = 0.f;
#pragma unroll
        for (int j = 0; j < 4; j++) { s1 += acc[i][j] * a1c[j]; s2 += acc[i][j] * a2c[j]; }
        for (int d = 1; d <= 16; d <<= 1) { s1 += __shfl_xor(s1, d); s2 += __shfl_xor(s2, d); }
        if (n < N) {
            size_t ro = ((size_t)h * N + n) * HID + tx * 4;
            ushort4 b4;
            b4.x = f2bf(acc[i][0]); b4.y = f2bf(acc[i][1]);
            b4.z = f2bf(acc[i][2]); b4.w = f2bf(acc[i][3]);
            *(ushort4*)(Whb + ro) = b4;
            if (tx == 0) { f1[h * N + n] = s1; f2[h * N + n] = s2; }
        }
    }
}

// K3: layer-1 fused masked-softmax + PV (R4 form, the measured 188us config).
// 16 streams x 16 lanes x 8 cols; {w, byteoff} float2 in LDS; bf16 hi free.
__global__ void gat1(const u16* __restrict__ Whb,
                     const float* __restrict__ f1, const float* __restrict__ f2,
                     const u16* __restrict__ nbr,
                     const int* __restrict__ ncnt,
                     float* __restrict__ hcat) {
    int bid = blockIdx.x;
    int h = bid / N, n = bid - h * N;
    int t = threadIdx.x;
    int s = t >> 4, op = t & 15;
    int cnt = ncnt[n];
    const u16* lst = nbr + (size_t)n * NBR_CAP;
    __shared__ float2 wm[NBR_CAP];        // {weight, byte-offset bits}
    __shared__ float accl[16][16][9];     // padded
    __shared__ float swl[16];

    float f1c = f1[h * N + n];
    for (int i = t; i < cnt; i += 256) {
        int m = lst[i];
        float z = f1c + f2[h * N + m];
        z = (z >= 0.f) ? z : ALPHA * z;
        wm[i] = make_float2(__expf(z), __uint_as_float((u32)m << 8));
    }
    __syncthreads();

    const char* base = (const char*)(Whb + (size_t)h * N * HID) + (op << 4);
    float acc[8] = {};
    float sw = 0.f;
    int j = s;
    for (; j + 16 < cnt; j += 32) {
        float2 p0 = wm[j];
        float2 p1 = wm[j + 16];
        const uint4 va = *(const uint4*)(base + __float_as_uint(p0.y));
        const uint4 vb = *(const uint4*)(base + __float_as_uint(p1.y));
        float w0 = p0.x, w1 = p1.x;
        acc[0] += w0 * __uint_as_float(va.x << 16);
        acc[1] += w0 * __uint_as_float(va.x);
        acc[2] += w0 * __uint_as_float(va.y << 16);
        acc[3] += w0 * __uint_as_float(va.y);
        acc[4] += w0 * __uint_as_float(va.z << 16);
        acc[5] += w0 * __uint_as_float(va.z);
        acc[6] += w0 * __uint_as_float(va.w << 16);
        acc[7] += w0 * __uint_as_float(va.w);
        acc[0] += w1 * __uint_as_float(vb.x << 16);
        acc[1] += w1 * __uint_as_float(vb.x);
        acc[2] += w1 * __uint_as_float(vb.y << 16);
        acc[3] += w1 * __uint_as_float(vb.y);
        acc[4] += w1 * __uint_as_float(vb.z << 16);
        acc[5] += w1 * __uint_as_float(vb.z);
        acc[6] += w1 * __uint_as_float(vb.w << 16);
        acc[7] += w1 * __uint_as_float(vb.w);
        sw += w0 + w1;
    }
    if (j < cnt) {
        float2 p0 = wm[j];
        const uint4 va = *(const uint4*)(base + __float_as_uint(p0.y));
        float w0 = p0.x;
        acc[0] += w0 * __uint_as_float(va.x << 16);
        acc[1] += w0 * __uint_as_float(va.x);
        acc[2] += w0 * __uint_as_float(va.y << 16);
        acc[3] += w0 * __uint_as_float(va.y);
        acc[4] += w0 * __uint_as_float(va.z << 16);
        acc[5] += w0 * __uint_as_float(va.z);
        acc[6] += w0 * __uint_as_float(va.w << 16);
        acc[7] += w0 * __uint_as_float(va.w);
        sw += w0;
    }
#pragma unroll
    for (int c = 0; c < 8; c++) accl[s][op][c] = acc[c];
    if (op == 0) swl[s] = sw;
    __syncthreads();

    if (t < 128) {
        int c = t;
        float r = 0.f;
#pragma unroll
        for (int k = 0; k < 16; k++) r += accl[k][c >> 3][c & 7];
        float swt = 0.f;
#pragma unroll
        for (int k = 0; k < 16; k++) swt += swl[k];
        r /= swt;
        r = (r > 0.f) ? r : expm1f(r);
        hcat[(size_t)n * (NH * HID) + h * HID + c] = r;
    }
}

// K4: partial = hcat(6000x1024) @ W_out(1024x128), split-K over 8 slices.
__global__ void gemm_out(const float* __restrict__ hcat,
                         const float* __restrict__ W_out,
                         float* __restrict__ partial) {
    int n0 = blockIdx.x * 64;
    int ks = blockIdx.y;
    __shared__ float xs[64][17];
    __shared__ float bs[16][128];
    int t = threadIdx.x;
    int tx = t & 31, ty = t >> 5;
    float acc[8][4] = {};
    int kbeg = ks * 128, kend = kbeg + 128;
    for (int k0 = kbeg; k0 < kend; k0 += 16) {
        for (int i = t; i < 64 * 16; i += 256) {
            int r = i >> 4, c = i & 15;
            int n = n0 + r;
            xs[r][c] = (n < N) ? hcat[(size_t)n * 1024 + k0 + c] : 0.f;
        }
        for (int i = t; i < 16 * 128; i += 256) {
            int r = i >> 7, c = i & 127;
            bs[r][c] = W_out[(size_t)(k0 + r) * HID + c];
        }
        __syncthreads();
#pragma unroll
        for (int kk = 0; kk < 16; kk++) {
            float b[4];
#pragma unroll
            for (int j = 0; j < 4; j++) b[j] = bs[kk][tx * 4 + j];
#pragma unroll
            for (int i = 0; i < 8; i++) {
                float a = xs[ty * 8 + i][kk];
#pragma unroll
                for (int j = 0; j < 4; j++) acc[i][j] += a * b[j];
            }
        }
        __syncthreads();
    }
    float* pout = partial + (size_t)ks * N * HID;
    for (int i = 0; i < 8; i++) {
        int n = n0 + ty * 8 + i;
        if (n < N) {
#pragma unroll
            for (int j = 0; j < 4; j++)
                pout[(size_t)n * HID + tx * 4 + j] = acc[i][j];
        }
    }
}

// K4b: sum the 8 K-split partials -> fp16 Wh2h shadow; fused g1/g2.
// grid 750 x 256; block owns 8 full rows (1024 floats).
__global__ void reduce_wh2(const float* __restrict__ partial,
                           const float* __restrict__ a_out,
                           u16* __restrict__ Wh2h,
                           float* __restrict__ g1, float* __restrict__ g2) {
    int idx = blockIdx.x * 256 + threadIdx.x;      // float4 index
    float4 v = *(const float4*)(partial + 4 * (size_t)idx);
#pragma unroll
    for (int s = 1; s < KSPLIT; s++) {
        const float4 q = *(const float4*)(partial + (size_t)s * N * HID + 4 * (size_t)idx);
        v.x += q.x; v.y += q.y; v.z += q.z; v.w += q.w;
    }
    ushort4 h4;
    h4.x = f2h(v.x); h4.y = f2h(v.y); h4.z = f2h(v.z); h4.w = f2h(v.w);
    *(ushort4*)(Wh2h + 4 * (size_t)idx) = h4;

    int row = idx >> 5, cg = idx & 31;
    float p1 = v.x * a_out[4 * cg] + v.y * a_out[4 * cg + 1]
             + v.z * a_out[4 * cg + 2] + v.w * a_out[4 * cg + 3];
    float p2 = v.x * a_out[HID + 4 * cg] + v.y * a_out[HID + 4 * cg + 1]
             + v.z * a_out[HID + 4 * cg + 2] + v.w * a_out[HID + 4 * cg + 3];
    for (int d = 1; d <= 16; d <<= 1) { p1 += __shfl_xor(p1, d); p2 += __shfl_xor(p2, d); }
    if ((threadIdx.x & 31) == 0) { g1[row] = p1; g2[row] = p2; }
}

// K6: layer-2 fused masked-softmax + PV, fp16 gather (gat1 mirror).
__global__ void gat2(const u16* __restrict__ Wh2h,
                     const float* __restrict__ g1, const float* __restrict__ g2,
                     const u16* __restrict__ nbr,
                     const int* __restrict__ ncnt,
                     float* __restrict__ out) {
    int n = blockIdx.x, t = threadIdx.x;
    int s = t >> 4, op = t & 15;
    int cnt = ncnt[n];
    const u16* lst = nbr + (size_t)n * NBR_CAP;
    __shared__ float2 wm[NBR_CAP];
    __shared__ float accl[16][16][9];
    __shared__ float swl[16];

    float g1c = g1[n];
    for (int i = t; i < cnt; i += 256) {
        int m = lst[i];
        float z = g1c + g2[m];
        z = (z >= 0.f) ? z : ALPHA * z;
        wm[i] = make_float2(__expf(z), __uint_as_float((u32)m << 8));
    }
    __syncthreads();

    const char* base = (const char*)Wh2h + (op << 4);
    float acc[8] = {};
    float sw = 0.f;
    int j = s;
    for (; j + 16 < cnt; j += 32) {
        float2 p0 = wm[j];
        float2 p1 = wm[j + 16];
        const uint4 va = *(const uint4*)(base + __float_as_uint(p0.y));
        const uint4 vb = *(const uint4*)(base + __float_as_uint(p1.y));
        float w0 = p0.x, w1 = p1.x;
        acc[0] += w0 * __half2float(__ushort_as_half((u16)(va.x & 0xffff)));
        acc[1] += w0 * __half2float(__ushort_as_half((u16)(va.x >> 16)));
        acc[2] += w0 * __half2float(__ushort_as_half((u16)(va.y & 0xffff)));
        acc[3] += w0 * __half2float(__ushort_as_half((u16)(va.y >> 16)));
        acc[4] += w0 * __half2float(__ushort_as_half((u16)(va.z & 0xffff)));
        acc[5] += w0 * __half2float(__ushort_as_half((u16)(va.z >> 16)));
        acc[6] += w0 * __half2float(__ushort_as_half((u16)(va.w & 0xffff)));
        acc[7] += w0 * __half2float(__ushort_as_half((u16)(va.w >> 16)));
        acc[0] += w1 * __half2float(__ushort_as_half((u16)(vb.x & 0xffff)));
        acc[1] += w1 * __half2float(__ushort_as_half((u16)(vb.x >> 16)));
        acc[2] += w1 * __half2float(__ushort_as_half((u16)(vb.y & 0xffff)));
        acc[3] += w1 * __half2float(__ushort_as_half((u16)(vb.y >> 16)));
        acc[4] += w1 * __half2float(__ushort_as_half((u16)(vb.z & 0xffff)));
        acc[5] += w1 * __half2float(__ushort_as_half((u16)(vb.z >> 16)));
        acc[6] += w1 * __half2float(__ushort_as_half((u16)(vb.w & 0xffff)));
        acc[7] += w1 * __half2float(__ushort_as_half((u16)(vb.w >> 16)));
        sw += w0 + w1;
    }
    if (j < cnt) {
        float2 p0 = wm[j];
        const uint4 va = *(const uint4*)(base + __float_as_uint(p0.y));
        float w0 = p0.x;
        acc[0] += w0 * __half2float(__ushort_as_half((u16)(va.x & 0xffff)));
        acc[1] += w0 * __half2float(__ushort_as_half((u16)(va.x >> 16)));
        acc[2] += w0 * __half2float(__ushort_as_half((u16)(va.y & 0xffff)));
        acc[3] += w0 * __half2float(__ushort_as_half((u16)(va.y >> 16)));
        acc[4] += w0 * __half2float(__ushort_as_half((u16)(va.z & 0xffff)));
        acc[5] += w0 * __half2float(__ushort_as_half((u16)(va.z >> 16)));
        acc[6] += w0 * __half2float(__ushort_as_half((u16)(va.w & 0xffff)));
        acc[7] += w0 * __half2float(__ushort_as_half((u16)(va.w >> 16)));
        sw += w0;
    }
#pragma unroll
    for (int c = 0; c < 8; c++) accl[s][op][c] = acc[c];
    if (op == 0) swl[s] = sw;
    __syncthreads();

    if (t < 128) {
        int c = t;
        float r = 0.f;
#pragma unroll
        for (int k = 0; k < 16; k++) r += accl[k][c >> 3][c & 7];
        float swt = 0.f;
#pragma unroll
        for (int k = 0; k < 16; k++) swt += swl[k];
        out[(size_t)n * HID + c] = r / swt;
    }
}

extern "C" void kernel_launch(void* const* d_in, const int* in_sizes, int n_in,
                              void* d_out, int out_size, void* d_ws, size_t ws_size,
                              hipStream_t stream) {
    const float* x       = (const float*)d_in[0];
    const float* adj     = (const float*)d_in[1];
    const float* W_heads = (const float*)d_in[2];
    const float* a_heads = (const float*)d_in[3];
    const float* W_out   = (const float*)d_in[4];
    const float* a_out   = (const float*)d_in[5];
    float* out = (float*)d_out;

    char* wsb = (char*)d_ws;
    size_t off = 0;
    auto alloc = [&](size_t bytes) {
        void* p = wsb + off;
        off += (bytes + 255) & ~(size_t)255;
        return p;
    };
    float* partial = (float*)alloc(sizeof(float) * (size_t)KSPLIT * N * HID); // 24.576 MB
    u16*   Whb  = (u16*)  alloc(sizeof(u16)   * (size_t)NH * N * HID);
    float* hcat = (float*)alloc(sizeof(float) * (size_t)N * NH * HID);
    u16*   Wh2h = (u16*)  alloc(sizeof(u16)   * (size_t)N * HID);
    float* f1   = (float*)alloc(sizeof(float) * (size_t)NH * N);
    float* f2   = (float*)alloc(sizeof(float) * (size_t)NH * N);
    float* g1   = (float*)alloc(sizeof(float) * (size_t)N);
    float* g2   = (float*)alloc(sizeof(float) * (size_t)N);
    u16* nbr    = (u16*)  alloc(sizeof(u16)   * (size_t)N * NBR_CAP);
    int* ncnt   = (int*)  alloc(sizeof(int)   * (size_t)N);

    hipLaunchKernelGGL(build_nbr, dim3(N), dim3(256), 0, stream, adj, nbr, ncnt);
    hipLaunchKernelGGL(gemm_wh, dim3((N + 63) / 64, NH), dim3(256), 0, stream,
                       x, W_heads, a_heads, Whb, f1, f2);
    hipLaunchKernelGGL(gat1, dim3(NH * N), dim3(256), 0, stream, Whb, f1, f2, nbr, ncnt, hcat);
    hipLaunchKernelGGL(gemm_out, dim3((N + 63) / 64, KSPLIT), dim3(256), 0, stream,
                       hcat, W_out, partial);
    hipLaunchKernelGGL(reduce_wh2, dim3(N * HID / 4 / 256), dim3(256), 0, stream,
                       partial, a_out, Wh2h, g1, g2);
    hipLaunchKernelGGL(gat2, dim3(N), dim3(256), 0, stream, Wh2h, g1, g2, nbr, ncnt, out);
}

// Round 14
// 321.222 us; speedup vs baseline: 1.6979x; 1.0728x over previous
//
#include <hip/hip_runtime.h>
#include <hip/hip_fp16.h>
#include <math.h>

#define N 6000
#define FIN 300
#define HID 128
#define NH 8
#define ALPHA 0.2f
#define NBR_CAP 512
#define KSPLIT 4

typedef unsigned short u16;
typedef unsigned int u32;
typedef short bf16x8 __attribute__((ext_vector_type(8)));
typedef float f32x4 __attribute__((ext_vector_type(4)));

static __device__ __forceinline__ u16 f2bf(float f) {
    u32 u = __float_as_uint(f);
    u32 r = (u + 0x7fff + ((u >> 16) & 1)) >> 16;   // round-to-nearest-even
    return (u16)r;
}
static __device__ __forceinline__ u16 f2h(float f) {
    return __half_as_ushort(__float2half(f));
}

// K0: build neighbor lists; per-wave private segment, 1 barrier, float4 loads
__global__ void build_nbr(const float* __restrict__ adj,
                          u16* __restrict__ nbr,
                          int* __restrict__ ncnt) {
    int n = blockIdx.x;
    int t = threadIdx.x;
    int lane = t & 63, w = t >> 6;
    __shared__ u16 lbuf[4][256];
    __shared__ int wc[4];
    const int seg = N / 4;                 // 1500
    int start = w * seg, end = start + seg;
    const float* row = adj + (size_t)n * N;
    int cnt = 0;
    for (int base = start; base < end; base += 256) {
        int m0 = base + 4 * lane;
        float4 v = make_float4(0.f, 0.f, 0.f, 0.f);
        if (m0 < end) v = *(const float4*)(row + m0);
#pragma unroll
        for (int c = 0; c < 4; c++) {
            float vc = (c == 0) ? v.x : (c == 1) ? v.y : (c == 2) ? v.z : v.w;
            bool p = vc > 0.5f;
            unsigned long long mask = __ballot(p);
            if (p) {
                int pos = cnt + __popcll(mask & ((1ull << lane) - 1ull));
                if (pos < 256) lbuf[w][pos] = (u16)(m0 + c);
            }
            cnt += __popcll(mask);
        }
    }
    if (cnt > 256) cnt = 256;
    if (lane == 0) wc[w] = cnt;
    __syncthreads();
    int offset = 0;
    for (int i = 0; i < w; i++) offset += wc[i];
    for (int i = lane; i < cnt; i += 64) {
        int idx = offset + i;
        if (idx < NBR_CAP) nbr[(size_t)n * NBR_CAP + idx] = lbuf[w][i];
    }
    if (t == 0) {
        int total = wc[0] + wc[1] + wc[2] + wc[3];
        ncnt[n] = total < NBR_CAP ? total : NBR_CAP;
    }
}

// K1: Whb(bf16) = x @ W_heads, fused f1/f2 epilogue (fp32 accurate).
__global__ void gemm_wh(const float* __restrict__ x,
                        const float* __restrict__ W,
                        const float* __restrict__ a_heads,
                        u16* __restrict__ Whb,
                        float* __restrict__ f1, float* __restrict__ f2) {
    int h = blockIdx.y;
    int n0 = blockIdx.x * 64;
    __shared__ float xs[64][21];
    __shared__ float bs[20][128];
    int t = threadIdx.x;
    int tx = t & 31, ty = t >> 5;
    float acc[8][4] = {};
    for (int k0 = 0; k0 < FIN; k0 += 20) {
        for (int i = t; i < 64 * 20; i += 256) {
            int r = i / 20, c = i - r * 20;
            int n = n0 + r;
            xs[r][c] = (n < N) ? x[(size_t)n * FIN + k0 + c] : 0.f;
        }
        for (int i = t; i < 20 * 128; i += 256) {
            int r = i >> 7, c = i & 127;
            bs[r][c] = W[((size_t)h * FIN + (k0 + r)) * HID + c];
        }
        __syncthreads();
#pragma unroll
        for (int kk = 0; kk < 20; kk++) {
            float b[4];
#pragma unroll
            for (int j = 0; j < 4; j++) b[j] = bs[kk][tx * 4 + j];
#pragma unroll
            for (int i = 0; i < 8; i++) {
                float a = xs[ty * 8 + i][kk];
#pragma unroll
                for (int j = 0; j < 4; j++) acc[i][j] += a * b[j];
            }
        }
        __syncthreads();
    }
    float a1c[4], a2c[4];
#pragma unroll
    for (int j = 0; j < 4; j++) {
        a1c[j] = a_heads[(size_t)h * 2 * HID + tx * 4 + j];
        a2c[j] = a_heads[(size_t)h * 2 * HID + HID + tx * 4 + j];
    }
    for (int i = 0; i < 8; i++) {
        int n = n0 + ty * 8 + i;
        float s1 = 0.f, s2 = 0.f;
#pragma unroll
        for (int j = 0; j < 4; j++) { s1 += acc[i][j] * a1c[j]; s2 += acc[i][j] * a2c[j]; }
        for (int d = 1; d <= 16; d <<= 1) { s1 += __shfl_xor(s1, d); s2 += __shfl_xor(s2, d); }
        if (n < N) {
            size_t ro = ((size_t)h * N + n) * HID + tx * 4;
            ushort4 b4;
            b4.x = f2bf(acc[i][0]); b4.y = f2bf(acc[i][1]);
            b4.z = f2bf(acc[i][2]); b4.w = f2bf(acc[i][3]);
            *(ushort4*)(Whb + ro) = b4;
            if (tx == 0) { f1[h * N + n] = s1; f2[h * N + n] = s2; }
        }
    }
}

// K1b: WoT[c][k] = bf16(W_out[k][c]); 128x1024 bf16 (256 KB)
__global__ void prep_wout(const float* __restrict__ W_out,
                          u16* __restrict__ WoT) {
    int idx = blockIdx.x * 256 + threadIdx.x;   // 131072 total
    int k = idx & 1023, c = idx >> 10;
    WoT[(size_t)c * 1024 + k] = f2bf(W_out[(size_t)k * HID + c]);
}

// K3: layer-1 fused masked-softmax + PV (R4 form, 188us config),
// now writing bf16 hcatb (halved write traffic; feeds MFMA gemm_out).
__global__ void gat1(const u16* __restrict__ Whb,
                     const float* __restrict__ f1, const float* __restrict__ f2,
                     const u16* __restrict__ nbr,
                     const int* __restrict__ ncnt,
                     u16* __restrict__ hcatb) {
    int bid = blockIdx.x;
    int h = bid / N, n = bid - h * N;
    int t = threadIdx.x;
    int s = t >> 4, op = t & 15;
    int cnt = ncnt[n];
    const u16* lst = nbr + (size_t)n * NBR_CAP;
    __shared__ float2 wm[NBR_CAP];        // {weight, byte-offset bits}
    __shared__ float accl[16][16][9];     // padded
    __shared__ float swl[16];

    float f1c = f1[h * N + n];
    for (int i = t; i < cnt; i += 256) {
        int m = lst[i];
        float z = f1c + f2[h * N + m];
        z = (z >= 0.f) ? z : ALPHA * z;
        wm[i] = make_float2(__expf(z), __uint_as_float((u32)m << 8));
    }
    __syncthreads();

    const char* base = (const char*)(Whb + (size_t)h * N * HID) + (op << 4);
    float acc[8] = {};
    float sw = 0.f;
    int j = s;
    for (; j + 16 < cnt; j += 32) {
        float2 p0 = wm[j];
        float2 p1 = wm[j + 16];
        const uint4 va = *(const uint4*)(base + __float_as_uint(p0.y));
        const uint4 vb = *(const uint4*)(base + __float_as_uint(p1.y));
        float w0 = p0.x, w1 = p1.x;
        acc[0] += w0 * __uint_as_float(va.x << 16);
        acc[1] += w0 * __uint_as_float(va.x);
        acc[2] += w0 * __uint_as_float(va.y << 16);
        acc[3] += w0 * __uint_as_float(va.y);
        acc[4] += w0 * __uint_as_float(va.z << 16);
        acc[5] += w0 * __uint_as_float(va.z);
        acc[6] += w0 * __uint_as_float(va.w << 16);
        acc[7] += w0 * __uint_as_float(va.w);
        acc[0] += w1 * __uint_as_float(vb.x << 16);
        acc[1] += w1 * __uint_as_float(vb.x);
        acc[2] += w1 * __uint_as_float(vb.y << 16);
        acc[3] += w1 * __uint_as_float(vb.y);
        acc[4] += w1 * __uint_as_float(vb.z << 16);
        acc[5] += w1 * __uint_as_float(vb.z);
        acc[6] += w1 * __uint_as_float(vb.w << 16);
        acc[7] += w1 * __uint_as_float(vb.w);
        sw += w0 + w1;
    }
    if (j < cnt) {
        float2 p0 = wm[j];
        const uint4 va = *(const uint4*)(base + __float_as_uint(p0.y));
        float w0 = p0.x;
        acc[0] += w0 * __uint_as_float(va.x << 16);
        acc[1] += w0 * __uint_as_float(va.x);
        acc[2] += w0 * __uint_as_float(va.y << 16);
        acc[3] += w0 * __uint_as_float(va.y);
        acc[4] += w0 * __uint_as_float(va.z << 16);
        acc[5] += w0 * __uint_as_float(va.z);
        acc[6] += w0 * __uint_as_float(va.w << 16);
        acc[7] += w0 * __uint_as_float(va.w);
        sw += w0;
    }
#pragma unroll
    for (int c = 0; c < 8; c++) accl[s][op][c] = acc[c];
    if (op == 0) swl[s] = sw;
    __syncthreads();

    if (t < 128) {
        int c = t;
        float r = 0.f;
#pragma unroll
        for (int k = 0; k < 16; k++) r += accl[k][c >> 3][c & 7];
        float swt = 0.f;
#pragma unroll
        for (int k = 0; k < 16; k++) swt += swl[k];
        r /= swt;
        r = (r > 0.f) ? r : expm1f(r);
        hcatb[(size_t)n * (NH * HID) + h * HID + c] = f2bf(r);
    }
}

// K4: partial = hcatb(6000x1024 bf16) @ W_out(bf16, via WoT), MFMA 16x16x32.
// KSPLIT=4 slices of K=256. Block: 64 rows x 128 cols, 4 waves (16 rows each).
// B staged per 128-k half in XOR-swizzled LDS (R11-verified pattern);
// A fragments loaded straight from global (each byte read exactly once).
__global__ __launch_bounds__(256)
void gemm_out_mfma(const u16* __restrict__ hcatb,
                   const u16* __restrict__ WoT,
                   float* __restrict__ partial) {
    int n0 = blockIdx.x * 64;
    int ks = blockIdx.y;                 // K slice of 256
    int t = threadIdx.x;
    int lane = t & 63, wid = t >> 6;
    int l4 = lane >> 4, lr = lane & 15;

    __shared__ u16 Bt[128][128];         // 32 KB, swizzled

    f32x4 acc[8];
#pragma unroll
    for (int ct = 0; ct < 8; ct++) acc[ct] = (f32x4){0.f, 0.f, 0.f, 0.f};

    int arow = n0 + 16 * wid + lr;
    const u16* asrc = hcatb + (size_t)arow * (NH * HID);
    bool avalid = (arow < N);

    for (int half = 0; half < 2; half++) {
        int kbeg = ks * 256 + half * 128;
        // stage Bt[c][0..127] = WoT[c][kbeg..kbeg+127], XOR-swizzled
        {
            int c = t >> 1, sh = t & 1;
            const u16* src = WoT + (size_t)c * 1024 + kbeg + sh * 64;
            int cx = (c & 7) << 3;
            uint4 v[8];
#pragma unroll
            for (int j = 0; j < 8; j++) v[j] = ((const uint4*)src)[j];
#pragma unroll
            for (int j = 0; j < 8; j++)
                *(uint4*)&Bt[c][(sh * 64 + 8 * j) ^ cx] = v[j];
        }
        __syncthreads();
#pragma unroll
        for (int kst = 0; kst < 4; kst++) {
            int kb = kst * 32 + 8 * l4;
            bf16x8 a = {0, 0, 0, 0, 0, 0, 0, 0};
            if (avalid) a = *(const bf16x8*)(asrc + kbeg + kb);
#pragma unroll
            for (int ct = 0; ct < 8; ct++) {
                int brow = 16 * ct + lr;
                bf16x8 b = *(const bf16x8*)&Bt[brow][kb ^ ((brow & 7) << 3)];
                acc[ct] = __builtin_amdgcn_mfma_f32_16x16x32_bf16(a, b, acc[ct], 0, 0, 0);
            }
        }
        __syncthreads();
    }
    // epilogue: C/D col = lane&15, row = 4*(lane>>4)+reg (HW-verified R10-R12)
    float* pout = partial + (size_t)ks * N * HID;
#pragma unroll
    for (int reg = 0; reg < 4; reg++) {
        int n = n0 + 16 * wid + 4 * l4 + reg;
        if (n < N) {
#pragma unroll
            for (int ct = 0; ct < 8; ct++)
                pout[(size_t)n * HID + 16 * ct + lr] = acc[ct][reg];
        }
    }
}

// K4b: sum the KSPLIT partials -> fp16 Wh2h shadow; fused g1/g2.
__global__ void reduce_wh2(const float* __restrict__ partial,
                           const float* __restrict__ a_out,
                           u16* __restrict__ Wh2h,
                           float* __restrict__ g1, float* __restrict__ g2) {
    int idx = blockIdx.x * 256 + threadIdx.x;      // float4 index
    float4 v = *(const float4*)(partial + 4 * (size_t)idx);
#pragma unroll
    for (int s = 1; s < KSPLIT; s++) {
        const float4 q = *(const float4*)(partial + (size_t)s * N * HID + 4 * (size_t)idx);
        v.x += q.x; v.y += q.y; v.z += q.z; v.w += q.w;
    }
    ushort4 h4;
    h4.x = f2h(v.x); h4.y = f2h(v.y); h4.z = f2h(v.z); h4.w = f2h(v.w);
    *(ushort4*)(Wh2h + 4 * (size_t)idx) = h4;

    int row = idx >> 5, cg = idx & 31;
    float p1 = v.x * a_out[4 * cg] + v.y * a_out[4 * cg + 1]
             + v.z * a_out[4 * cg + 2] + v.w * a_out[4 * cg + 3];
    float p2 = v.x * a_out[HID + 4 * cg] + v.y * a_out[HID + 4 * cg + 1]
             + v.z * a_out[HID + 4 * cg + 2] + v.w * a_out[HID + 4 * cg + 3];
    for (int d = 1; d <= 16; d <<= 1) { p1 += __shfl_xor(p1, d); p2 += __shfl_xor(p2, d); }
    if ((threadIdx.x & 31) == 0) { g1[row] = p1; g2[row] = p2; }
}

// K6: layer-2 fused masked-softmax + PV, fp16 gather (gat1 mirror).
__global__ void gat2(const u16* __restrict__ Wh2h,
                     const float* __restrict__ g1, const float* __restrict__ g2,
                     const u16* __restrict__ nbr,
                     const int* __restrict__ ncnt,
                     float* __restrict__ out) {
    int n = blockIdx.x, t = threadIdx.x;
    int s = t >> 4, op = t & 15;
    int cnt = ncnt[n];
    const u16* lst = nbr + (size_t)n * NBR_CAP;
    __shared__ float2 wm[NBR_CAP];
    __shared__ float accl[16][16][9];
    __shared__ float swl[16];

    float g1c = g1[n];
    for (int i = t; i < cnt; i += 256) {
        int m = lst[i];
        float z = g1c + g2[m];
        z = (z >= 0.f) ? z : ALPHA * z;
        wm[i] = make_float2(__expf(z), __uint_as_float((u32)m << 8));
    }
    __syncthreads();

    const char* base = (const char*)Wh2h + (op << 4);
    float acc[8] = {};
    float sw = 0.f;
    int j = s;
    for (; j + 16 < cnt; j += 32) {
        float2 p0 = wm[j];
        float2 p1 = wm[j + 16];
        const uint4 va = *(const uint4*)(base + __float_as_uint(p0.y));
        const uint4 vb = *(const uint4*)(base + __float_as_uint(p1.y));
        float w0 = p0.x, w1 = p1.x;
        acc[0] += w0 * __half2float(__ushort_as_half((u16)(va.x & 0xffff)));
        acc[1] += w0 * __half2float(__ushort_as_half((u16)(va.x >> 16)));
        acc[2] += w0 * __half2float(__ushort_as_half((u16)(va.y & 0xffff)));
        acc[3] += w0 * __half2float(__ushort_as_half((u16)(va.y >> 16)));
        acc[4] += w0 * __half2float(__ushort_as_half((u16)(va.z & 0xffff)));
        acc[5] += w0 * __half2float(__ushort_as_half((u16)(va.z >> 16)));
        acc[6] += w0 * __half2float(__ushort_as_half((u16)(va.w & 0xffff)));
        acc[7] += w0 * __half2float(__ushort_as_half((u16)(va.w >> 16)));
        acc[0] += w1 * __half2float(__ushort_as_half((u16)(vb.x & 0xffff)));
        acc[1] += w1 * __half2float(__ushort_as_half((u16)(vb.x >> 16)));
        acc[2] += w1 * __half2float(__ushort_as_half((u16)(vb.y & 0xffff)));
        acc[3] += w1 * __half2float(__ushort_as_half((u16)(vb.y >> 16)));
        acc[4] += w1 * __half2float(__ushort_as_half((u16)(vb.z & 0xffff)));
        acc[5] += w1 * __half2float(__ushort_as_half((u16)(vb.z >> 16)));
        acc[6] += w1 * __half2float(__ushort_as_half((u16)(vb.w & 0xffff)));
        acc[7] += w1 * __half2float(__ushort_as_half((u16)(vb.w >> 16)));
        sw += w0 + w1;
    }
    if (j < cnt) {
        float2 p0 = wm[j];
        const uint4 va = *(const uint4*)(base + __float_as_uint(p0.y));
        float w0 = p0.x;
        acc[0] += w0 * __half2float(__ushort_as_half((u16)(va.x & 0xffff)));
        acc[1] += w0 * __half2float(__ushort_as_half((u16)(va.x >> 16)));
        acc[2] += w0 * __half2float(__ushort_as_half((u16)(va.y & 0xffff)));
        acc[3] += w0 * __half2float(__ushort_as_half((u16)(va.y >> 16)));
        acc[4] += w0 * __half2float(__ushort_as_half((u16)(va.z & 0xffff)));
        acc[5] += w0 * __half2float(__ushort_as_half((u16)(va.z >> 16)));
        acc[6] += w0 * __half2float(__ushort_as_half((u16)(va.w & 0xffff)));
        acc[7] += w0 * __half2float(__ushort_as_half((u16)(va.w >> 16)));
        sw += w0;
    }
#pragma unroll
    for (int c = 0; c < 8; c++) accl[s][op][c] = acc[c];
    if (op == 0) swl[s] = sw;
    __syncthreads();

    if (t < 128) {
        int c = t;
        float r = 0.f;
#pragma unroll
        for (int k = 0; k < 16; k++) r += accl[k][c >> 3][c & 7];
        float swt = 0.f;
#pragma unroll
        for (int k = 0; k < 16; k++) swt += swl[k];
        out[(size_t)n * HID + c] = r / swt;
    }
}

extern "C" void kernel_launch(void* const* d_in, const int* in_sizes, int n_in,
                              void* d_out, int out_size, void* d_ws, size_t ws_size,
                              hipStream_t stream) {
    const float* x       = (const float*)d_in[0];
    const float* adj     = (const float*)d_in[1];
    const float* W_heads = (const float*)d_in[2];
    const float* a_heads = (const float*)d_in[3];
    const float* W_out   = (const float*)d_in[4];
    const float* a_out   = (const float*)d_in[5];
    float* out = (float*)d_out;

    char* wsb = (char*)d_ws;
    size_t off = 0;
    auto alloc = [&](size_t bytes) {
        void* p = wsb + off;
        off += (bytes + 255) & ~(size_t)255;
        return p;
    };
    float* partial = (float*)alloc(sizeof(float) * (size_t)KSPLIT * N * HID); // 12.3 MB
    u16*   Whb  = (u16*)  alloc(sizeof(u16)   * (size_t)NH * N * HID);        // 12.3 MB
    u16*   hcatb= (u16*)  alloc(sizeof(u16)   * (size_t)N * NH * HID);        // 12.3 MB
    u16*   WoT  = (u16*)  alloc(sizeof(u16)   * (size_t)HID * 1024);          // 256 KB
    u16*   Wh2h = (u16*)  alloc(sizeof(u16)   * (size_t)N * HID);
    float* f1   = (float*)alloc(sizeof(float) * (size_t)NH * N);
    float* f2   = (float*)alloc(sizeof(float) * (size_t)NH * N);
    float* g1   = (float*)alloc(sizeof(float) * (size_t)N);
    float* g2   = (float*)alloc(sizeof(float) * (size_t)N);
    u16* nbr    = (u16*)  alloc(sizeof(u16)   * (size_t)N * NBR_CAP);
    int* ncnt   = (int*)  alloc(sizeof(int)   * (size_t)N);

    hipLaunchKernelGGL(build_nbr, dim3(N), dim3(256), 0, stream, adj, nbr, ncnt);
    hipLaunchKernelGGL(gemm_wh, dim3((N + 63) / 64, NH), dim3(256), 0, stream,
                       x, W_heads, a_heads, Whb, f1, f2);
    hipLaunchKernelGGL(prep_wout, dim3(512), dim3(256), 0, stream, W_out, WoT);
    hipLaunchKernelGGL(gat1, dim3(NH * N), dim3(256), 0, stream, Whb, f1, f2, nbr, ncnt, hcatb);
    hipLaunchKernelGGL(gemm_out_mfma, dim3((N + 63) / 64, KSPLIT), dim3(256), 0, stream,
                       hcatb, WoT, partial);
    hipLaunchKernelGGL(reduce_wh2, dim3(N * HID / 4 / 256), dim3(256), 0, stream,
                       partial, a_out, Wh2h, g1, g2);
    hipLaunchKernelGGL(gat2, dim3(N), dim3(256), 0, stream, Wh2h, g1, g2, nbr, ncnt, out);
}

// Round 15
// 281.473 us; speedup vs baseline: 1.9376x; 1.1412x over previous
//
#include <hip/hip_runtime.h>
#include <hip/hip_fp16.h>
#include <math.h>

#define N 6000
#define FIN 300
#define HID 128
#define NH 8
#define ALPHA 0.2f
#define NBR_CAP 512
#define KSPLIT 4
#define KPAD 384           // FIN padded to 3x128 for MFMA chunks

typedef unsigned short u16;
typedef unsigned int u32;
typedef short bf16x8 __attribute__((ext_vector_type(8)));
typedef float f32x4 __attribute__((ext_vector_type(4)));

static __device__ __forceinline__ u16 f2bf(float f) {
    u32 u = __float_as_uint(f);
    u32 r = (u + 0x7fff + ((u >> 16) & 1)) >> 16;   // round-to-nearest-even
    return (u16)r;
}
static __device__ __forceinline__ u16 f2h(float f) {
    return __half_as_ushort(__float2half(f));
}

// K0: build neighbor lists; per-wave private segment, 1 barrier, float4 loads
__global__ void build_nbr(const float* __restrict__ adj,
                          u16* __restrict__ nbr,
                          int* __restrict__ ncnt) {
    int n = blockIdx.x;
    int t = threadIdx.x;
    int lane = t & 63, w = t >> 6;
    __shared__ u16 lbuf[4][256];
    __shared__ int wc[4];
    const int seg = N / 4;                 // 1500
    int start = w * seg, end = start + seg;
    const float* row = adj + (size_t)n * N;
    int cnt = 0;
    for (int base = start; base < end; base += 256) {
        int m0 = base + 4 * lane;
        float4 v = make_float4(0.f, 0.f, 0.f, 0.f);
        if (m0 < end) v = *(const float4*)(row + m0);
#pragma unroll
        for (int c = 0; c < 4; c++) {
            float vc = (c == 0) ? v.x : (c == 1) ? v.y : (c == 2) ? v.z : v.w;
            bool p = vc > 0.5f;
            unsigned long long mask = __ballot(p);
            if (p) {
                int pos = cnt + __popcll(mask & ((1ull << lane) - 1ull));
                if (pos < 256) lbuf[w][pos] = (u16)(m0 + c);
            }
            cnt += __popcll(mask);
        }
    }
    if (cnt > 256) cnt = 256;
    if (lane == 0) wc[w] = cnt;
    __syncthreads();
    int offset = 0;
    for (int i = 0; i < w; i++) offset += wc[i];
    for (int i = lane; i < cnt; i += 64) {
        int idx = offset + i;
        if (idx < NBR_CAP) nbr[(size_t)n * NBR_CAP + idx] = lbuf[w][i];
    }
    if (t == 0) {
        int total = wc[0] + wc[1] + wc[2] + wc[3];
        ncnt[n] = total < NBR_CAP ? total : NBR_CAP;
    }
}

// K1: fused prep — xb (bf16 padded x), WbT (bf16 W transposed+padded),
// WoT (bf16 W_out transposed), av1/av2 (fp32 W@a per head).
// grid = 9000 + 1536 + 512 + 8 = 11056 blocks x 256.
__global__ void prep_all(const float* __restrict__ x,
                         const float* __restrict__ W,
                         const float* __restrict__ W_out,
                         const float* __restrict__ a_heads,
                         u16* __restrict__ xb,
                         u16* __restrict__ WbT,
                         u16* __restrict__ WoT,
                         float* __restrict__ av1, float* __restrict__ av2) {
    int bid = blockIdx.x, t = threadIdx.x;
    if (bid < 9000) {                       // xb[n][k], 6000x384
        int idx = bid * 256 + t;
        int n = idx / KPAD, k = idx - n * KPAD;
        xb[idx] = (k < FIN) ? f2bf(x[(size_t)n * FIN + k]) : (u16)0;
    } else if (bid < 9000 + 1536) {         // WbT[h][c][k], 8x128x384
        int idx = (bid - 9000) * 256 + t;
        int k = idx % KPAD;
        int c = (idx / KPAD) & 127;
        int h = idx / (KPAD * HID);
        WbT[idx] = (k < FIN) ? f2bf(W[((size_t)h * FIN + k) * HID + c]) : (u16)0;
    } else if (bid < 9000 + 1536 + 512) {   // WoT[c][k], 128x1024
        int idx = (bid - 9000 - 1536) * 256 + t;
        int k = idx & 1023, c = idx >> 10;
        WoT[idx] = f2bf(W_out[(size_t)k * HID + c]);
    } else {                                // av1/av2[h][0..320)
        int h = bid - (9000 + 1536 + 512);
        __shared__ float a1s[HID], a2s[HID];
        if (t < HID) {
            a1s[t] = a_heads[(size_t)h * 2 * HID + t];
            a2s[t] = a_heads[(size_t)h * 2 * HID + HID + t];
        }
        __syncthreads();
        for (int f = t; f < 320; f += 256) {
            float s1 = 0.f, s2 = 0.f;
            if (f < FIN) {
                const float* wr = W + ((size_t)h * FIN + f) * HID;
#pragma unroll 4
                for (int o = 0; o < HID; o++) { s1 += wr[o] * a1s[o]; s2 += wr[o] * a2s[o]; }
            }
            av1[h * 320 + f] = s1;
            av2[h * 320 + f] = s2;
        }
    }
}

// K2: f1[h][n] = x[n]·av1[h], f2 likewise — fp32-exact logits.
// one block per n; wave w handles heads 2w, 2w+1.
__global__ void calc_f(const float* __restrict__ x,
                       const float* __restrict__ av1, const float* __restrict__ av2,
                       float* __restrict__ f1, float* __restrict__ f2) {
    int n = blockIdx.x, t = threadIdx.x;
    int lane = t & 63, w = t >> 6;
    __shared__ float xsh[320];
    for (int i = t; i < 320; i += 256)
        xsh[i] = (i < FIN) ? x[(size_t)n * FIN + i] : 0.f;
    __syncthreads();
#pragma unroll
    for (int hh = 0; hh < 2; hh++) {
        int h = 2 * w + hh;
        const float* a1 = av1 + h * 320;
        const float* a2 = av2 + h * 320;
        float s1 = 0.f, s2 = 0.f;
#pragma unroll
        for (int i = 0; i < 5; i++) {
            float xv = xsh[lane + 64 * i];
            s1 += xv * a1[lane + 64 * i];
            s2 += xv * a2[lane + 64 * i];
        }
        for (int d = 1; d <= 32; d <<= 1) { s1 += __shfl_xor(s1, d); s2 += __shfl_xor(s2, d); }
        if (lane == 0) { f1[h * N + n] = s1; f2[h * N + n] = s2; }
    }
}

// K3a: Whb[h][n][c] = bf16( xb @ WbT[h] ), MFMA 16x16x32, K=384 in 3 chunks.
// Same verified structure as gemm_out_mfma (R13).
__global__ __launch_bounds__(256)
void gemm_wh_mfma(const u16* __restrict__ xb,
                  const u16* __restrict__ WbT,
                  u16* __restrict__ Whb) {
    int n0 = blockIdx.x * 64;
    int h = blockIdx.y;
    int t = threadIdx.x;
    int lane = t & 63, wid = t >> 6;
    int l4 = lane >> 4, lr = lane & 15;

    __shared__ u16 Bt[128][128];         // 32 KB, swizzled

    f32x4 acc[8];
#pragma unroll
    for (int ct = 0; ct < 8; ct++) acc[ct] = (f32x4){0.f, 0.f, 0.f, 0.f};

    int arow = n0 + 16 * wid + lr;
    const u16* asrc = xb + (size_t)arow * KPAD;
    bool avalid = (arow < N);

    for (int half = 0; half < 3; half++) {
        int kbeg = half * 128;
        {
            int c = t >> 1, sh = t & 1;
            const u16* src = WbT + ((size_t)h * HID + c) * KPAD + kbeg + sh * 64;
            int cx = (c & 7) << 3;
            uint4 v[8];
#pragma unroll
            for (int j = 0; j < 8; j++) v[j] = ((const uint4*)src)[j];
#pragma unroll
            for (int j = 0; j < 8; j++)
                *(uint4*)&Bt[c][(sh * 64 + 8 * j) ^ cx] = v[j];
        }
        __syncthreads();
#pragma unroll
        for (int kst = 0; kst < 4; kst++) {
            int kb = kst * 32 + 8 * l4;
            bf16x8 a = {0, 0, 0, 0, 0, 0, 0, 0};
            if (avalid) a = *(const bf16x8*)(asrc + kbeg + kb);
#pragma unroll
            for (int ct = 0; ct < 8; ct++) {
                int brow = 16 * ct + lr;
                bf16x8 b = *(const bf16x8*)&Bt[brow][kb ^ ((brow & 7) << 3)];
                acc[ct] = __builtin_amdgcn_mfma_f32_16x16x32_bf16(a, b, acc[ct], 0, 0, 0);
            }
        }
        __syncthreads();
    }
    // epilogue: C/D col = lane&15, row = 4*(lane>>4)+reg (HW-verified R10-R13)
#pragma unroll
    for (int reg = 0; reg < 4; reg++) {
        int n = n0 + 16 * wid + 4 * l4 + reg;
        if (n < N) {
            u16* orow = Whb + ((size_t)h * N + n) * HID;
#pragma unroll
            for (int ct = 0; ct < 8; ct++)
                orow[16 * ct + lr] = f2bf(acc[ct][reg]);
        }
    }
}

// K3: layer-1 fused masked-softmax + PV (R4 form, 188us config), bf16 out.
__global__ void gat1(const u16* __restrict__ Whb,
                     const float* __restrict__ f1, const float* __restrict__ f2,
                     const u16* __restrict__ nbr,
                     const int* __restrict__ ncnt,
                     u16* __restrict__ hcatb) {
    int bid = blockIdx.x;
    int h = bid / N, n = bid - h * N;
    int t = threadIdx.x;
    int s = t >> 4, op = t & 15;
    int cnt = ncnt[n];
    const u16* lst = nbr + (size_t)n * NBR_CAP;
    __shared__ float2 wm[NBR_CAP];        // {weight, byte-offset bits}
    __shared__ float accl[16][16][9];     // padded
    __shared__ float swl[16];

    float f1c = f1[h * N + n];
    for (int i = t; i < cnt; i += 256) {
        int m = lst[i];
        float z = f1c + f2[h * N + m];
        z = (z >= 0.f) ? z : ALPHA * z;
        wm[i] = make_float2(__expf(z), __uint_as_float((u32)m << 8));
    }
    __syncthreads();

    const char* base = (const char*)(Whb + (size_t)h * N * HID) + (op << 4);
    float acc[8] = {};
    float sw = 0.f;
    int j = s;
    for (; j + 16 < cnt; j += 32) {
        float2 p0 = wm[j];
        float2 p1 = wm[j + 16];
        const uint4 va = *(const uint4*)(base + __float_as_uint(p0.y));
        const uint4 vb = *(const uint4*)(base + __float_as_uint(p1.y));
        float w0 = p0.x, w1 = p1.x;
        acc[0] += w0 * __uint_as_float(va.x << 16);
        acc[1] += w0 * __uint_as_float(va.x);
        acc[2] += w0 * __uint_as_float(va.y << 16);
        acc[3] += w0 * __uint_as_float(va.y);
        acc[4] += w0 * __uint_as_float(va.z << 16);
        acc[5] += w0 * __uint_as_float(va.z);
        acc[6] += w0 * __uint_as_float(va.w << 16);
        acc[7] += w0 * __uint_as_float(va.w);
        acc[0] += w1 * __uint_as_float(vb.x << 16);
        acc[1] += w1 * __uint_as_float(vb.x);
        acc[2] += w1 * __uint_as_float(vb.y << 16);
        acc[3] += w1 * __uint_as_float(vb.y);
        acc[4] += w1 * __uint_as_float(vb.z << 16);
        acc[5] += w1 * __uint_as_float(vb.z);
        acc[6] += w1 * __uint_as_float(vb.w << 16);
        acc[7] += w1 * __uint_as_float(vb.w);
        sw += w0 + w1;
    }
    if (j < cnt) {
        float2 p0 = wm[j];
        const uint4 va = *(const uint4*)(base + __float_as_uint(p0.y));
        float w0 = p0.x;
        acc[0] += w0 * __uint_as_float(va.x << 16);
        acc[1] += w0 * __uint_as_float(va.x);
        acc[2] += w0 * __uint_as_float(va.y << 16);
        acc[3] += w0 * __uint_as_float(va.y);
        acc[4] += w0 * __uint_as_float(va.z << 16);
        acc[5] += w0 * __uint_as_float(va.z);
        acc[6] += w0 * __uint_as_float(va.w << 16);
        acc[7] += w0 * __uint_as_float(va.w);
        sw += w0;
    }
#pragma unroll
    for (int c = 0; c < 8; c++) accl[s][op][c] = acc[c];
    if (op == 0) swl[s] = sw;
    __syncthreads();

    if (t < 128) {
        int c = t;
        float r = 0.f;
#pragma unroll
        for (int k = 0; k < 16; k++) r += accl[k][c >> 3][c & 7];
        float swt = 0.f;
#pragma unroll
        for (int k = 0; k < 16; k++) swt += swl[k];
        r /= swt;
        r = (r > 0.f) ? r : expm1f(r);
        hcatb[(size_t)n * (NH * HID) + h * HID + c] = f2bf(r);
    }
}

// K4: partial = hcatb(6000x1024 bf16) @ WoT, MFMA 16x16x32, KSPLIT=4.
__global__ __launch_bounds__(256)
void gemm_out_mfma(const u16* __restrict__ hcatb,
                   const u16* __restrict__ WoT,
                   float* __restrict__ partial) {
    int n0 = blockIdx.x * 64;
    int ks = blockIdx.y;                 // K slice of 256
    int t = threadIdx.x;
    int lane = t & 63, wid = t >> 6;
    int l4 = lane >> 4, lr = lane & 15;

    __shared__ u16 Bt[128][128];         // 32 KB, swizzled

    f32x4 acc[8];
#pragma unroll
    for (int ct = 0; ct < 8; ct++) acc[ct] = (f32x4){0.f, 0.f, 0.f, 0.f};

    int arow = n0 + 16 * wid + lr;
    const u16* asrc = hcatb + (size_t)arow * (NH * HID);
    bool avalid = (arow < N);

    for (int half = 0; half < 2; half++) {
        int kbeg = ks * 256 + half * 128;
        {
            int c = t >> 1, sh = t & 1;
            const u16* src = WoT + (size_t)c * 1024 + kbeg + sh * 64;
            int cx = (c & 7) << 3;
            uint4 v[8];
#pragma unroll
            for (int j = 0; j < 8; j++) v[j] = ((const uint4*)src)[j];
#pragma unroll
            for (int j = 0; j < 8; j++)
                *(uint4*)&Bt[c][(sh * 64 + 8 * j) ^ cx] = v[j];
        }
        __syncthreads();
#pragma unroll
        for (int kst = 0; kst < 4; kst++) {
            int kb = kst * 32 + 8 * l4;
            bf16x8 a = {0, 0, 0, 0, 0, 0, 0, 0};
            if (avalid) a = *(const bf16x8*)(asrc + kbeg + kb);
#pragma unroll
            for (int ct = 0; ct < 8; ct++) {
                int brow = 16 * ct + lr;
                bf16x8 b = *(const bf16x8*)&Bt[brow][kb ^ ((brow & 7) << 3)];
                acc[ct] = __builtin_amdgcn_mfma_f32_16x16x32_bf16(a, b, acc[ct], 0, 0, 0);
            }
        }
        __syncthreads();
    }
    float* pout = partial + (size_t)ks * N * HID;
#pragma unroll
    for (int reg = 0; reg < 4; reg++) {
        int n = n0 + 16 * wid + 4 * l4 + reg;
        if (n < N) {
#pragma unroll
            for (int ct = 0; ct < 8; ct++)
                pout[(size_t)n * HID + 16 * ct + lr] = acc[ct][reg];
        }
    }
}

// K4b: sum the KSPLIT partials -> fp16 Wh2h shadow; fused g1/g2 (fp32).
__global__ void reduce_wh2(const float* __restrict__ partial,
                           const float* __restrict__ a_out,
                           u16* __restrict__ Wh2h,
                           float* __restrict__ g1, float* __restrict__ g2) {
    int idx = blockIdx.x * 256 + threadIdx.x;      // float4 index
    float4 v = *(const float4*)(partial + 4 * (size_t)idx);
#pragma unroll
    for (int s = 1; s < KSPLIT; s++) {
        const float4 q = *(const float4*)(partial + (size_t)s * N * HID + 4 * (size_t)idx);
        v.x += q.x; v.y += q.y; v.z += q.z; v.w += q.w;
    }
    ushort4 h4;
    h4.x = f2h(v.x); h4.y = f2h(v.y); h4.z = f2h(v.z); h4.w = f2h(v.w);
    *(ushort4*)(Wh2h + 4 * (size_t)idx) = h4;

    int row = idx >> 5, cg = idx & 31;
    float p1 = v.x * a_out[4 * cg] + v.y * a_out[4 * cg + 1]
             + v.z * a_out[4 * cg + 2] + v.w * a_out[4 * cg + 3];
    float p2 = v.x * a_out[HID + 4 * cg] + v.y * a_out[HID + 4 * cg + 1]
             + v.z * a_out[HID + 4 * cg + 2] + v.w * a_out[HID + 4 * cg + 3];
    for (int d = 1; d <= 16; d <<= 1) { p1 += __shfl_xor(p1, d); p2 += __shfl_xor(p2, d); }
    if ((threadIdx.x & 31) == 0) { g1[row] = p1; g2[row] = p2; }
}

// K6: layer-2 fused masked-softmax + PV, fp16 gather.
__global__ void gat2(const u16* __restrict__ Wh2h,
                     const float* __restrict__ g1, const float* __restrict__ g2,
                     const u16* __restrict__ nbr,
                     const int* __restrict__ ncnt,
                     float* __restrict__ out) {
    int n = blockIdx.x, t = threadIdx.x;
    int s = t >> 4, op = t & 15;
    int cnt = ncnt[n];
    const u16* lst = nbr + (size_t)n * NBR_CAP;
    __shared__ float2 wm[NBR_CAP];
    __shared__ float accl[16][16][9];
    __shared__ float swl[16];

    float g1c = g1[n];
    for (int i = t; i < cnt; i += 256) {
        int m = lst[i];
        float z = g1c + g2[m];
        z = (z >= 0.f) ? z : ALPHA * z;
        wm[i] = make_float2(__expf(z), __uint_as_float((u32)m << 8));
    }
    __syncthreads();

    const char* base = (const char*)Wh2h + (op << 4);
    float acc[8] = {};
    float sw = 0.f;
    int j = s;
    for (; j + 16 < cnt; j += 32) {
        float2 p0 = wm[j];
        float2 p1 = wm[j + 16];
        const uint4 va = *(const uint4*)(base + __float_as_uint(p0.y));
        const uint4 vb = *(const uint4*)(base + __float_as_uint(p1.y));
        float w0 = p0.x, w1 = p1.x;
        acc[0] += w0 * __half2float(__ushort_as_half((u16)(va.x & 0xffff)));
        acc[1] += w0 * __half2float(__ushort_as_half((u16)(va.x >> 16)));
        acc[2] += w0 * __half2float(__ushort_as_half((u16)(va.y & 0xffff)));
        acc[3] += w0 * __half2float(__ushort_as_half((u16)(va.y >> 16)));
        acc[4] += w0 * __half2float(__ushort_as_half((u16)(va.z & 0xffff)));
        acc[5] += w0 * __half2float(__ushort_as_half((u16)(va.z >> 16)));
        acc[6] += w0 * __half2float(__ushort_as_half((u16)(va.w & 0xffff)));
        acc[7] += w0 * __half2float(__ushort_as_half((u16)(va.w >> 16)));
        acc[0] += w1 * __half2float(__ushort_as_half((u16)(vb.x & 0xffff)));
        acc[1] += w1 * __half2float(__ushort_as_half((u16)(vb.x >> 16)));
        acc[2] += w1 * __half2float(__ushort_as_half((u16)(vb.y & 0xffff)));
        acc[3] += w1 * __half2float(__ushort_as_half((u16)(vb.y >> 16)));
        acc[4] += w1 * __half2float(__ushort_as_half((u16)(vb.z & 0xffff)));
        acc[5] += w1 * __half2float(__ushort_as_half((u16)(vb.z >> 16)));
        acc[6] += w1 * __half2float(__ushort_as_half((u16)(vb.w & 0xffff)));
        acc[7] += w1 * __half2float(__ushort_as_half((u16)(vb.w >> 16)));
        sw += w0 + w1;
    }
    if (j < cnt) {
        float2 p0 = wm[j];
        const uint4 va = *(const uint4*)(base + __float_as_uint(p0.y));
        float w0 = p0.x;
        acc[0] += w0 * __half2float(__ushort_as_half((u16)(va.x & 0xffff)));
        acc[1] += w0 * __half2float(__ushort_as_half((u16)(va.x >> 16)));
        acc[2] += w0 * __half2float(__ushort_as_half((u16)(va.y & 0xffff)));
        acc[3] += w0 * __half2float(__ushort_as_half((u16)(va.y >> 16)));
        acc[4] += w0 * __half2float(__ushort_as_half((u16)(va.z & 0xffff)));
        acc[5] += w0 * __half2float(__ushort_as_half((u16)(va.z >> 16)));
        acc[6] += w0 * __half2float(__ushort_as_half((u16)(va.w & 0xffff)));
        acc[7] += w0 * __half2float(__ushort_as_half((u16)(va.w >> 16)));
        sw += w0;
    }
#pragma unroll
    for (int c = 0; c < 8; c++) accl[s][op][c] = acc[c];
    if (op == 0) swl[s] = sw;
    __syncthreads();

    if (t < 128) {
        int c = t;
        float r = 0.f;
#pragma unroll
        for (int k = 0; k < 16; k++) r += accl[k][c >> 3][c & 7];
        float swt = 0.f;
#pragma unroll
        for (int k = 0; k < 16; k++) swt += swl[k];
        out[(size_t)n * HID + c] = r / swt;
    }
}

extern "C" void kernel_launch(void* const* d_in, const int* in_sizes, int n_in,
                              void* d_out, int out_size, void* d_ws, size_t ws_size,
                              hipStream_t stream) {
    const float* x       = (const float*)d_in[0];
    const float* adj     = (const float*)d_in[1];
    const float* W_heads = (const float*)d_in[2];
    const float* a_heads = (const float*)d_in[3];
    const float* W_out   = (const float*)d_in[4];
    const float* a_out   = (const float*)d_in[5];
    float* out = (float*)d_out;

    char* wsb = (char*)d_ws;
    size_t off = 0;
    auto alloc = [&](size_t bytes) {
        void* p = wsb + off;
        off += (bytes + 255) & ~(size_t)255;
        return p;
    };
    float* partial = (float*)alloc(sizeof(float) * (size_t)KSPLIT * N * HID); // 12.3 MB
    u16*   Whb  = (u16*)  alloc(sizeof(u16)   * (size_t)NH * N * HID);        // 12.3 MB
    u16*   hcatb= (u16*)  alloc(sizeof(u16)   * (size_t)N * NH * HID);        // 12.3 MB
    u16*   xb   = (u16*)  alloc(sizeof(u16)   * (size_t)N * KPAD);            // 4.6 MB
    u16*   WbT  = (u16*)  alloc(sizeof(u16)   * (size_t)NH * HID * KPAD);     // 786 KB
    u16*   WoT  = (u16*)  alloc(sizeof(u16)   * (size_t)HID * 1024);          // 256 KB
    u16*   Wh2h = (u16*)  alloc(sizeof(u16)   * (size_t)N * HID);
    float* av1  = (float*)alloc(sizeof(float) * (size_t)NH * 320);
    float* av2  = (float*)alloc(sizeof(float) * (size_t)NH * 320);
    float* f1   = (float*)alloc(sizeof(float) * (size_t)NH * N);
    float* f2   = (float*)alloc(sizeof(float) * (size_t)NH * N);
    float* g1   = (float*)alloc(sizeof(float) * (size_t)N);
    float* g2   = (float*)alloc(sizeof(float) * (size_t)N);
    u16* nbr    = (u16*)  alloc(sizeof(u16)   * (size_t)N * NBR_CAP);
    int* ncnt   = (int*)  alloc(sizeof(int)   * (size_t)N);

    hipLaunchKernelGGL(build_nbr, dim3(N), dim3(256), 0, stream, adj, nbr, ncnt);
    hipLaunchKernelGGL(prep_all, dim3(9000 + 1536 + 512 + 8), dim3(256), 0, stream,
                       x, W_heads, W_out, a_heads, xb, WbT, WoT, av1, av2);
    hipLaunchKernelGGL(calc_f, dim3(N), dim3(256), 0, stream, x, av1, av2, f1, f2);
    hipLaunchKernelGGL(gemm_wh_mfma, dim3((N + 63) / 64, NH), dim3(256), 0, stream,
                       xb, WbT, Whb);
    hipLaunchKernelGGL(gat1, dim3(NH * N), dim3(256), 0, stream, Whb, f1, f2, nbr, ncnt, hcatb);
    hipLaunchKernelGGL(gemm_out_mfma, dim3((N + 63) / 64, KSPLIT), dim3(256), 0, stream,
                       hcatb, WoT, partial);
    hipLaunchKernelGGL(reduce_wh2, dim3(N * HID / 4 / 256), dim3(256), 0, stream,
                       partial, a_out, Wh2h, g1, g2);
    hipLaunchKernelGGL(gat2, dim3(N), dim3(256), 0, stream, Wh2h, g1, g2, nbr, ncnt, out);
}

// Round 16
// 278.680 us; speedup vs baseline: 1.9571x; 1.0100x over previous
//
#include <hip/hip_runtime.h>
#include <hip/hip_fp16.h>
#include <math.h>

#define N 6000
#define FIN 300
#define HID 128
#define NH 8
#define ALPHA 0.2f
#define NBR_CAP 512
#define KSPLIT 4
#define KPAD 384           // FIN padded to 3x128 for MFMA chunks

typedef unsigned short u16;
typedef unsigned int u32;
typedef short bf16x8 __attribute__((ext_vector_type(8)));
typedef float f32x4 __attribute__((ext_vector_type(4)));

static __device__ __forceinline__ u16 f2bf(float f) {
    u32 u = __float_as_uint(f);
    u32 r = (u + 0x7fff + ((u >> 16) & 1)) >> 16;   // round-to-nearest-even
    return (u16)r;
}
static __device__ __forceinline__ u16 f2h(float f) {
    return __half_as_ushort(__float2half(f));
}

// K0+K1 fused: blocks [0,6000) build neighbor lists; remaining blocks do
// bf16 prep (xb, WbT, WoT) and av GEMVs. Saves a launch; overlaps adj HBM
// read with prep compute.
#define PREP_NBLK (6000 + 9000 + 1536 + 512 + 8)
__global__ void prep_all(const float* __restrict__ adj,
                         const float* __restrict__ x,
                         const float* __restrict__ W,
                         const float* __restrict__ W_out,
                         const float* __restrict__ a_heads,
                         u16* __restrict__ nbr, int* __restrict__ ncnt,
                         u16* __restrict__ xb,
                         u16* __restrict__ WbT,
                         u16* __restrict__ WoT,
                         float* __restrict__ av1, float* __restrict__ av2) {
    int bid = blockIdx.x, t = threadIdx.x;
    __shared__ u16 lbuf[4][256];
    __shared__ int wc[4];
    __shared__ float a1s[HID], a2s[HID];
    if (bid < 6000) {                       // ---- build_nbr (R15-verified)
        int n = bid;
        int lane = t & 63, w = t >> 6;
        const int seg = N / 4;              // 1500
        int start = w * seg, end = start + seg;
        const float* row = adj + (size_t)n * N;
        int cnt = 0;
        for (int base = start; base < end; base += 256) {
            int m0 = base + 4 * lane;
            float4 v = make_float4(0.f, 0.f, 0.f, 0.f);
            if (m0 < end) v = *(const float4*)(row + m0);
#pragma unroll
            for (int c = 0; c < 4; c++) {
                float vc = (c == 0) ? v.x : (c == 1) ? v.y : (c == 2) ? v.z : v.w;
                bool p = vc > 0.5f;
                unsigned long long mask = __ballot(p);
                if (p) {
                    int pos = cnt + __popcll(mask & ((1ull << lane) - 1ull));
                    if (pos < 256) lbuf[w][pos] = (u16)(m0 + c);
                }
                cnt += __popcll(mask);
            }
        }
        if (cnt > 256) cnt = 256;
        if (lane == 0) wc[w] = cnt;
        __syncthreads();
        int offset = 0;
        for (int i = 0; i < w; i++) offset += wc[i];
        for (int i = lane; i < cnt; i += 64) {
            int idx = offset + i;
            if (idx < NBR_CAP) nbr[(size_t)n * NBR_CAP + idx] = lbuf[w][i];
        }
        if (t == 0) {
            int total = wc[0] + wc[1] + wc[2] + wc[3];
            ncnt[n] = total < NBR_CAP ? total : NBR_CAP;
        }
    } else if (bid < 6000 + 9000) {         // xb[n][k], 6000x384
        int idx = (bid - 6000) * 256 + t;
        int n = idx / KPAD, k = idx - n * KPAD;
        xb[idx] = (k < FIN) ? f2bf(x[(size_t)n * FIN + k]) : (u16)0;
    } else if (bid < 6000 + 9000 + 1536) {  // WbT[h][c][k], 8x128x384
        int idx = (bid - 6000 - 9000) * 256 + t;
        int k = idx % KPAD;
        int c = (idx / KPAD) & 127;
        int h = idx / (KPAD * HID);
        WbT[idx] = (k < FIN) ? f2bf(W[((size_t)h * FIN + k) * HID + c]) : (u16)0;
    } else if (bid < 6000 + 9000 + 1536 + 512) {   // WoT[c][k], 128x1024
        int idx = (bid - 6000 - 9000 - 1536) * 256 + t;
        int k = idx & 1023, c = idx >> 10;
        WoT[idx] = f2bf(W_out[(size_t)k * HID + c]);
    } else {                                // av1/av2[h][0..320)
        int h = bid - (6000 + 9000 + 1536 + 512);
        if (t < HID) {
            a1s[t] = a_heads[(size_t)h * 2 * HID + t];
            a2s[t] = a_heads[(size_t)h * 2 * HID + HID + t];
        }
        __syncthreads();
        for (int f = t; f < 320; f += 256) {
            float s1 = 0.f, s2 = 0.f;
            if (f < FIN) {
                const float* wr = W + ((size_t)h * FIN + f) * HID;
#pragma unroll 4
                for (int o = 0; o < HID; o++) { s1 += wr[o] * a1s[o]; s2 += wr[o] * a2s[o]; }
            }
            av1[h * 320 + f] = s1;
            av2[h * 320 + f] = s2;
        }
    }
}

// K2: f1[h][n] = x[n]·av1[h], f2 likewise — fp32-exact logits.
__global__ void calc_f(const float* __restrict__ x,
                       const float* __restrict__ av1, const float* __restrict__ av2,
                       float* __restrict__ f1, float* __restrict__ f2) {
    int n = blockIdx.x, t = threadIdx.x;
    int lane = t & 63, w = t >> 6;
    __shared__ float xsh[320];
    for (int i = t; i < 320; i += 256)
        xsh[i] = (i < FIN) ? x[(size_t)n * FIN + i] : 0.f;
    __syncthreads();
#pragma unroll
    for (int hh = 0; hh < 2; hh++) {
        int h = 2 * w + hh;
        const float* a1 = av1 + h * 320;
        const float* a2 = av2 + h * 320;
        float s1 = 0.f, s2 = 0.f;
#pragma unroll
        for (int i = 0; i < 5; i++) {
            float xv = xsh[lane + 64 * i];
            s1 += xv * a1[lane + 64 * i];
            s2 += xv * a2[lane + 64 * i];
        }
        for (int d = 1; d <= 32; d <<= 1) { s1 += __shfl_xor(s1, d); s2 += __shfl_xor(s2, d); }
        if (lane == 0) { f1[h * N + n] = s1; f2[h * N + n] = s2; }
    }
}

// K3a: Whb[h][n][c] = bf16( xb @ WbT[h] ), MFMA 16x16x32, K=384 in 3 chunks.
__global__ __launch_bounds__(256)
void gemm_wh_mfma(const u16* __restrict__ xb,
                  const u16* __restrict__ WbT,
                  u16* __restrict__ Whb) {
    int n0 = blockIdx.x * 64;
    int h = blockIdx.y;
    int t = threadIdx.x;
    int lane = t & 63, wid = t >> 6;
    int l4 = lane >> 4, lr = lane & 15;

    __shared__ u16 Bt[128][128];         // 32 KB, swizzled

    f32x4 acc[8];
#pragma unroll
    for (int ct = 0; ct < 8; ct++) acc[ct] = (f32x4){0.f, 0.f, 0.f, 0.f};

    int arow = n0 + 16 * wid + lr;
    const u16* asrc = xb + (size_t)arow * KPAD;
    bool avalid = (arow < N);

    for (int half = 0; half < 3; half++) {
        int kbeg = half * 128;
        {
            int c = t >> 1, sh = t & 1;
            const u16* src = WbT + ((size_t)h * HID + c) * KPAD + kbeg + sh * 64;
            int cx = (c & 7) << 3;
            uint4 v[8];
#pragma unroll
            for (int j = 0; j < 8; j++) v[j] = ((const uint4*)src)[j];
#pragma unroll
            for (int j = 0; j < 8; j++)
                *(uint4*)&Bt[c][(sh * 64 + 8 * j) ^ cx] = v[j];
        }
        __syncthreads();
#pragma unroll
        for (int kst = 0; kst < 4; kst++) {
            int kb = kst * 32 + 8 * l4;
            bf16x8 a = {0, 0, 0, 0, 0, 0, 0, 0};
            if (avalid) a = *(const bf16x8*)(asrc + kbeg + kb);
#pragma unroll
            for (int ct = 0; ct < 8; ct++) {
                int brow = 16 * ct + lr;
                bf16x8 b = *(const bf16x8*)&Bt[brow][kb ^ ((brow & 7) << 3)];
                acc[ct] = __builtin_amdgcn_mfma_f32_16x16x32_bf16(a, b, acc[ct], 0, 0, 0);
            }
        }
        __syncthreads();
    }
#pragma unroll
    for (int reg = 0; reg < 4; reg++) {
        int n = n0 + 16 * wid + 4 * l4 + reg;
        if (n < N) {
            u16* orow = Whb + ((size_t)h * N + n) * HID;
#pragma unroll
            for (int ct = 0; ct < 8; ct++)
                orow[16 * ct + lr] = f2bf(acc[ct][reg]);
        }
    }
}

// K3: layer-1 fused masked-softmax + PV; sw hoisted out of the hot loop
// (per-thread partial in phase A + butterfly/LDS reduce -> uniform swt).
__global__ void gat1(const u16* __restrict__ Whb,
                     const float* __restrict__ f1, const float* __restrict__ f2,
                     const u16* __restrict__ nbr,
                     const int* __restrict__ ncnt,
                     u16* __restrict__ hcatb) {
    int bid = blockIdx.x;
    int h = bid / N, n = bid - h * N;
    int t = threadIdx.x;
    int s = t >> 4, op = t & 15;
    int cnt = ncnt[n];
    const u16* lst = nbr + (size_t)n * NBR_CAP;
    __shared__ float2 wm[NBR_CAP];        // {weight, byte-offset bits}
    __shared__ float accl[16][16][9];     // padded
    __shared__ float red4[4];

    float f1c = f1[h * N + n];
    float pw = 0.f;
    for (int i = t; i < cnt; i += 256) {
        int m = lst[i];
        float z = f1c + f2[h * N + m];
        z = (z >= 0.f) ? z : ALPHA * z;
        float wv = __expf(z);
        pw += wv;
        wm[i] = make_float2(wv, __uint_as_float((u32)m << 8));
    }
    for (int d = 1; d <= 32; d <<= 1) pw += __shfl_xor(pw, d);
    if ((t & 63) == 0) red4[t >> 6] = pw;
    __syncthreads();
    float swt = red4[0] + red4[1] + red4[2] + red4[3];

    const char* base = (const char*)(Whb + (size_t)h * N * HID) + (op << 4);
    float acc[8] = {};
    int j = s;
    for (; j + 16 < cnt; j += 32) {
        float2 p0 = wm[j];
        float2 p1 = wm[j + 16];
        const uint4 va = *(const uint4*)(base + __float_as_uint(p0.y));
        const uint4 vb = *(const uint4*)(base + __float_as_uint(p1.y));
        float w0 = p0.x, w1 = p1.x;
        acc[0] += w0 * __uint_as_float(va.x << 16);
        acc[1] += w0 * __uint_as_float(va.x);
        acc[2] += w0 * __uint_as_float(va.y << 16);
        acc[3] += w0 * __uint_as_float(va.y);
        acc[4] += w0 * __uint_as_float(va.z << 16);
        acc[5] += w0 * __uint_as_float(va.z);
        acc[6] += w0 * __uint_as_float(va.w << 16);
        acc[7] += w0 * __uint_as_float(va.w);
        acc[0] += w1 * __uint_as_float(vb.x << 16);
        acc[1] += w1 * __uint_as_float(vb.x);
        acc[2] += w1 * __uint_as_float(vb.y << 16);
        acc[3] += w1 * __uint_as_float(vb.y);
        acc[4] += w1 * __uint_as_float(vb.z << 16);
        acc[5] += w1 * __uint_as_float(vb.z);
        acc[6] += w1 * __uint_as_float(vb.w << 16);
        acc[7] += w1 * __uint_as_float(vb.w);
    }
    if (j < cnt) {
        float2 p0 = wm[j];
        const uint4 va = *(const uint4*)(base + __float_as_uint(p0.y));
        float w0 = p0.x;
        acc[0] += w0 * __uint_as_float(va.x << 16);
        acc[1] += w0 * __uint_as_float(va.x);
        acc[2] += w0 * __uint_as_float(va.y << 16);
        acc[3] += w0 * __uint_as_float(va.y);
        acc[4] += w0 * __uint_as_float(va.z << 16);
        acc[5] += w0 * __uint_as_float(va.z);
        acc[6] += w0 * __uint_as_float(va.w << 16);
        acc[7] += w0 * __uint_as_float(va.w);
    }
#pragma unroll
    for (int c = 0; c < 8; c++) accl[s][op][c] = acc[c];
    __syncthreads();

    if (t < 128) {
        int c = t;
        float r = 0.f;
#pragma unroll
        for (int k = 0; k < 16; k++) r += accl[k][c >> 3][c & 7];
        r /= swt;
        r = (r > 0.f) ? r : expm1f(r);
        hcatb[(size_t)n * (NH * HID) + h * HID + c] = f2bf(r);
    }
}

// K4: partial = hcatb(6000x1024 bf16) @ WoT, MFMA 16x16x32, KSPLIT=4.
__global__ __launch_bounds__(256)
void gemm_out_mfma(const u16* __restrict__ hcatb,
                   const u16* __restrict__ WoT,
                   float* __restrict__ partial) {
    int n0 = blockIdx.x * 64;
    int ks = blockIdx.y;                 // K slice of 256
    int t = threadIdx.x;
    int lane = t & 63, wid = t >> 6;
    int l4 = lane >> 4, lr = lane & 15;

    __shared__ u16 Bt[128][128];         // 32 KB, swizzled

    f32x4 acc[8];
#pragma unroll
    for (int ct = 0; ct < 8; ct++) acc[ct] = (f32x4){0.f, 0.f, 0.f, 0.f};

    int arow = n0 + 16 * wid + lr;
    const u16* asrc = hcatb + (size_t)arow * (NH * HID);
    bool avalid = (arow < N);

    for (int half = 0; half < 2; half++) {
        int kbeg = ks * 256 + half * 128;
        {
            int c = t >> 1, sh = t & 1;
            const u16* src = WoT + (size_t)c * 1024 + kbeg + sh * 64;
            int cx = (c & 7) << 3;
            uint4 v[8];
#pragma unroll
            for (int j = 0; j < 8; j++) v[j] = ((const uint4*)src)[j];
#pragma unroll
            for (int j = 0; j < 8; j++)
                *(uint4*)&Bt[c][(sh * 64 + 8 * j) ^ cx] = v[j];
        }
        __syncthreads();
#pragma unroll
        for (int kst = 0; kst < 4; kst++) {
            int kb = kst * 32 + 8 * l4;
            bf16x8 a = {0, 0, 0, 0, 0, 0, 0, 0};
            if (avalid) a = *(const bf16x8*)(asrc + kbeg + kb);
#pragma unroll
            for (int ct = 0; ct < 8; ct++) {
                int brow = 16 * ct + lr;
                bf16x8 b = *(const bf16x8*)&Bt[brow][kb ^ ((brow & 7) << 3)];
                acc[ct] = __builtin_amdgcn_mfma_f32_16x16x32_bf16(a, b, acc[ct], 0, 0, 0);
            }
        }
        __syncthreads();
    }
    float* pout = partial + (size_t)ks * N * HID;
#pragma unroll
    for (int reg = 0; reg < 4; reg++) {
        int n = n0 + 16 * wid + 4 * l4 + reg;
        if (n < N) {
#pragma unroll
            for (int ct = 0; ct < 8; ct++)
                pout[(size_t)n * HID + 16 * ct + lr] = acc[ct][reg];
        }
    }
}

// K4b: sum the KSPLIT partials -> fp16 Wh2h shadow; fused g1/g2 (fp32).
__global__ void reduce_wh2(const float* __restrict__ partial,
                           const float* __restrict__ a_out,
                           u16* __restrict__ Wh2h,
                           float* __restrict__ g1, float* __restrict__ g2) {
    int idx = blockIdx.x * 256 + threadIdx.x;      // float4 index
    float4 v = *(const float4*)(partial + 4 * (size_t)idx);
#pragma unroll
    for (int s = 1; s < KSPLIT; s++) {
        const float4 q = *(const float4*)(partial + (size_t)s * N * HID + 4 * (size_t)idx);
        v.x += q.x; v.y += q.y; v.z += q.z; v.w += q.w;
    }
    ushort4 h4;
    h4.x = f2h(v.x); h4.y = f2h(v.y); h4.z = f2h(v.z); h4.w = f2h(v.w);
    *(ushort4*)(Wh2h + 4 * (size_t)idx) = h4;

    int row = idx >> 5, cg = idx & 31;
    float p1 = v.x * a_out[4 * cg] + v.y * a_out[4 * cg + 1]
             + v.z * a_out[4 * cg + 2] + v.w * a_out[4 * cg + 3];
    float p2 = v.x * a_out[HID + 4 * cg] + v.y * a_out[HID + 4 * cg + 1]
             + v.z * a_out[HID + 4 * cg + 2] + v.w * a_out[HID + 4 * cg + 3];
    for (int d = 1; d <= 16; d <<= 1) { p1 += __shfl_xor(p1, d); p2 += __shfl_xor(p2, d); }
    if ((threadIdx.x & 31) == 0) { g1[row] = p1; g2[row] = p2; }
}

// K6: layer-2 fused masked-softmax + PV, fp16 gather; sw hoisted like gat1.
__global__ void gat2(const u16* __restrict__ Wh2h,
                     const float* __restrict__ g1, const float* __restrict__ g2,
                     const u16* __restrict__ nbr,
                     const int* __restrict__ ncnt,
                     float* __restrict__ out) {
    int n = blockIdx.x, t = threadIdx.x;
    int s = t >> 4, op = t & 15;
    int cnt = ncnt[n];
    const u16* lst = nbr + (size_t)n * NBR_CAP;
    __shared__ float2 wm[NBR_CAP];
    __shared__ float accl[16][16][9];
    __shared__ float red4[4];

    float g1c = g1[n];
    float pw = 0.f;
    for (int i = t; i < cnt; i += 256) {
        int m = lst[i];
        float z = g1c + g2[m];
        z = (z >= 0.f) ? z : ALPHA * z;
        float wv = __expf(z);
        pw += wv;
        wm[i] = make_float2(wv, __uint_as_float((u32)m << 8));
    }
    for (int d = 1; d <= 32; d <<= 1) pw += __shfl_xor(pw, d);
    if ((t & 63) == 0) red4[t >> 6] = pw;
    __syncthreads();
    float swt = red4[0] + red4[1] + red4[2] + red4[3];

    const char* base = (const char*)Wh2h + (op << 4);
    float acc[8] = {};
    int j = s;
    for (; j + 16 < cnt; j += 32) {
        float2 p0 = wm[j];
        float2 p1 = wm[j + 16];
        const uint4 va = *(const uint4*)(base + __float_as_uint(p0.y));
        const uint4 vb = *(const uint4*)(base + __float_as_uint(p1.y));
        float w0 = p0.x, w1 = p1.x;
        acc[0] += w0 * __half2float(__ushort_as_half((u16)(va.x & 0xffff)));
        acc[1] += w0 * __half2float(__ushort_as_half((u16)(va.x >> 16)));
        acc[2] += w0 * __half2float(__ushort_as_half((u16)(va.y & 0xffff)));
        acc[3] += w0 * __half2float(__ushort_as_half((u16)(va.y >> 16)));
        acc[4] += w0 * __half2float(__ushort_as_half((u16)(va.z & 0xffff)));
        acc[5] += w0 * __half2float(__ushort_as_half((u16)(va.z >> 16)));
        acc[6] += w0 * __half2float(__ushort_as_half((u16)(va.w & 0xffff)));
        acc[7] += w0 * __half2float(__ushort_as_half((u16)(va.w >> 16)));
        acc[0] += w1 * __half2float(__ushort_as_half((u16)(vb.x & 0xffff)));
        acc[1] += w1 * __half2float(__ushort_as_half((u16)(vb.x >> 16)));
        acc[2] += w1 * __half2float(__ushort_as_half((u16)(vb.y & 0xffff)));
        acc[3] += w1 * __half2float(__ushort_as_half((u16)(vb.y >> 16)));
        acc[4] += w1 * __half2float(__ushort_as_half((u16)(vb.z & 0xffff)));
        acc[5] += w1 * __half2float(__ushort_as_half((u16)(vb.z >> 16)));
        acc[6] += w1 * __half2float(__ushort_as_half((u16)(vb.w & 0xffff)));
        acc[7] += w1 * __half2float(__ushort_as_half((u16)(vb.w >> 16)));
    }
    if (j < cnt) {
        float2 p0 = wm[j];
        const uint4 va = *(const uint4*)(base + __float_as_uint(p0.y));
        float w0 = p0.x;
        acc[0] += w0 * __half2float(__ushort_as_half((u16)(va.x & 0xffff)));
        acc[1] += w0 * __half2float(__ushort_as_half((u16)(va.x >> 16)));
        acc[2] += w0 * __half2float(__ushort_as_half((u16)(va.y & 0xffff)));
        acc[3] += w0 * __half2float(__ushort_as_half((u16)(va.y >> 16)));
        acc[4] += w0 * __half2float(__ushort_as_half((u16)(va.z & 0xffff)));
        acc[5] += w0 * __half2float(__ushort_as_half((u16)(va.z >> 16)));
        acc[6] += w0 * __half2float(__ushort_as_half((u16)(va.w & 0xffff)));
        acc[7] += w0 * __half2float(__ushort_as_half((u16)(va.w >> 16)));
    }
#pragma unroll
    for (int c = 0; c < 8; c++) accl[s][op][c] = acc[c];
    __syncthreads();

    if (t < 128) {
        int c = t;
        float r = 0.f;
#pragma unroll
        for (int k = 0; k < 16; k++) r += accl[k][c >> 3][c & 7];
        out[(size_t)n * HID + c] = r / swt;
    }
}

extern "C" void kernel_launch(void* const* d_in, const int* in_sizes, int n_in,
                              void* d_out, int out_size, void* d_ws, size_t ws_size,
                              hipStream_t stream) {
    const float* x       = (const float*)d_in[0];
    const float* adj     = (const float*)d_in[1];
    const float* W_heads = (const float*)d_in[2];
    const float* a_heads = (const float*)d_in[3];
    const float* W_out   = (const float*)d_in[4];
    const float* a_out   = (const float*)d_in[5];
    float* out = (float*)d_out;

    char* wsb = (char*)d_ws;
    size_t off = 0;
    auto alloc = [&](size_t bytes) {
        void* p = wsb + off;
        off += (bytes + 255) & ~(size_t)255;
        return p;
    };
    float* partial = (float*)alloc(sizeof(float) * (size_t)KSPLIT * N * HID); // 12.3 MB
    u16*   Whb  = (u16*)  alloc(sizeof(u16)   * (size_t)NH * N * HID);        // 12.3 MB
    u16*   hcatb= (u16*)  alloc(sizeof(u16)   * (size_t)N * NH * HID);        // 12.3 MB
    u16*   xb   = (u16*)  alloc(sizeof(u16)   * (size_t)N * KPAD);            // 4.6 MB
    u16*   WbT  = (u16*)  alloc(sizeof(u16)   * (size_t)NH * HID * KPAD);     // 786 KB
    u16*   WoT  = (u16*)  alloc(sizeof(u16)   * (size_t)HID * 1024);          // 256 KB
    u16*   Wh2h = (u16*)  alloc(sizeof(u16)   * (size_t)N * HID);
    float* av1  = (float*)alloc(sizeof(float) * (size_t)NH * 320);
    float* av2  = (float*)alloc(sizeof(float) * (size_t)NH * 320);
    float* f1   = (float*)alloc(sizeof(float) * (size_t)NH * N);
    float* f2   = (float*)alloc(sizeof(float) * (size_t)NH * N);
    float* g1   = (float*)alloc(sizeof(float) * (size_t)N);
    float* g2   = (float*)alloc(sizeof(float) * (size_t)N);
    u16* nbr    = (u16*)  alloc(sizeof(u16)   * (size_t)N * NBR_CAP);
    int* ncnt   = (int*)  alloc(sizeof(int)   * (size_t)N);

    hipLaunchKernelGGL(prep_all, dim3(PREP_NBLK), dim3(256), 0, stream,
                       adj, x, W_heads, W_out, a_heads, nbr, ncnt, xb, WbT, WoT, av1, av2);
    hipLaunchKernelGGL(calc_f, dim3(N), dim3(256), 0, stream, x, av1, av2, f1, f2);
    hipLaunchKernelGGL(gemm_wh_mfma, dim3((N + 63) / 64, NH), dim3(256), 0, stream,
                       xb, WbT, Whb);
    hipLaunchKernelGGL(gat1, dim3(NH * N), dim3(256), 0, stream, Whb, f1, f2, nbr, ncnt, hcatb);
    hipLaunchKernelGGL(gemm_out_mfma, dim3((N + 63) / 64, KSPLIT), dim3(256), 0, stream,
                       hcatb, WoT, partial);
    hipLaunchKernelGGL(reduce_wh2, dim3(N * HID / 4 / 256), dim3(256), 0, stream,
                       partial, a_out, Wh2h, g1, g2);
    hipLaunchKernelGGL(gat2, dim3(N), dim3(256), 0, stream, Wh2h, g1, g2, nbr, ncnt, out);
}